// Round 1
// baseline (2674.759 us; speedup 1.0000x reference)
//
#include <hip/hip_runtime.h>
#include <hip/hip_bf16.h>

#define N_NODES 40000
#define N_EDGES 640000
#define HID 128
#define NB 64
#define F_IN 16
#define BN_EPS 1e-5f

// ---------------------------------------------------------------------------
// Edge message + scatter, layer 0 (d = 16)
// msg = relu(x[src] + ea0*We[0,:] + ea1*We[1,:] + be); aggr[dst] += msg
// one thread per (edge, 4 features)
// ---------------------------------------------------------------------------
__global__ __launch_bounds__(256) void edge_msg16(
    const float* __restrict__ x, const int* __restrict__ ei,
    const float* __restrict__ ea, const float* __restrict__ We,
    const float* __restrict__ be, float* __restrict__ aggr) {
  int gid = blockIdx.x * 256 + threadIdx.x;
  if (gid >= N_EDGES * 4) return;
  int e = gid >> 2;
  int c4 = (gid & 3) << 2;
  int s = ei[e];
  int d = ei[N_EDGES + e];
  float a0 = ea[2 * e], a1 = ea[2 * e + 1];
  float4 xv = *(const float4*)(x + s * F_IN + c4);
  float4 w0 = *(const float4*)(We + c4);
  float4 w1 = *(const float4*)(We + F_IN + c4);
  float4 bv = *(const float4*)(be + c4);
  float4 m;
  m.x = fmaxf(xv.x + a0 * w0.x + a1 * w1.x + bv.x, 0.f);
  m.y = fmaxf(xv.y + a0 * w0.y + a1 * w1.y + bv.y, 0.f);
  m.z = fmaxf(xv.z + a0 * w0.z + a1 * w1.z + bv.z, 0.f);
  m.w = fmaxf(xv.w + a0 * w0.w + a1 * w1.w + bv.w, 0.f);
  float* p = aggr + d * F_IN + c4;
  atomicAdd(p + 0, m.x);
  atomicAdd(p + 1, m.y);
  atomicAdd(p + 2, m.z);
  atomicAdd(p + 3, m.w);
}

// ---------------------------------------------------------------------------
// Edge message + scatter, d = 128. one thread per (edge, 4 features)
// ---------------------------------------------------------------------------
__global__ __launch_bounds__(256) void edge_msg128(
    const float* __restrict__ x, const int* __restrict__ ei,
    const float* __restrict__ ea, const float* __restrict__ We,
    const float* __restrict__ be, float* __restrict__ aggr) {
  int gid = blockIdx.x * 256 + threadIdx.x;
  int e = gid >> 5;
  int c4 = (gid & 31) << 2;
  int s = ei[e];
  int d = ei[N_EDGES + e];
  float a0 = ea[2 * e], a1 = ea[2 * e + 1];
  float4 xv = *(const float4*)(x + s * HID + c4);
  float4 w0 = *(const float4*)(We + c4);
  float4 w1 = *(const float4*)(We + HID + c4);
  float4 bv = *(const float4*)(be + c4);
  float4 m;
  m.x = fmaxf(xv.x + a0 * w0.x + a1 * w1.x + bv.x, 0.f);
  m.y = fmaxf(xv.y + a0 * w0.y + a1 * w1.y + bv.y, 0.f);
  m.z = fmaxf(xv.z + a0 * w0.z + a1 * w1.z + bv.z, 0.f);
  m.w = fmaxf(xv.w + a0 * w0.w + a1 * w1.w + bv.w, 0.f);
  float* p = aggr + d * HID + c4;
  atomicAdd(p + 0, m.x);
  atomicAdd(p + 1, m.y);
  atomicAdd(p + 2, m.z);
  atomicAdd(p + 3, m.w);
}

// ---------------------------------------------------------------------------
// Tiled f32 GEMM: out[N,128] = A[N,K] @ W[K,128] + bias
//   BN_PRO: A element passed through relu(a*scale[k]+shift[k]) at staging.
//   STATS : accumulate per-column sum/sumsq of out (pre-relu) into stat[256].
//   RELU  : relu on output.
// Block: 256 threads, 32 rows. K tiled by 32 (or 16 when K==16).
// ---------------------------------------------------------------------------
template <int K, bool BN_PRO, bool STATS, bool RELU>
__global__ __launch_bounds__(256) void gemm_fused(
    const float* __restrict__ A, const float* __restrict__ W,
    const float* __restrict__ bias, const float* __restrict__ scale,
    const float* __restrict__ shift, float* __restrict__ out,
    float* __restrict__ stat) {
  constexpr int KT = (K < 32) ? K : 32;
  __shared__ float Wl[KT][HID];
  __shared__ float Al[32][KT];
  __shared__ float red[8][2][HID];

  int tid = threadIdx.x;
  int cg = tid & 31;          // column group (4 cols each)
  int rg = tid >> 5;          // row group (4 rows each)
  int c = cg << 2;
  int row0 = blockIdx.x * 32;

  float4 acc[4];
#pragma unroll
  for (int i = 0; i < 4; i++) acc[i] = make_float4(0.f, 0.f, 0.f, 0.f);

  for (int kt = 0; kt < K; kt += KT) {
    // stage W tile
    for (int i = tid; i < KT * (HID / 4); i += 256) {
      int k = i >> 5;
      int cc = (i & 31) << 2;
      *(float4*)&Wl[k][cc] = *(const float4*)(W + (kt + k) * HID + cc);
    }
    // stage A tile (32 rows x KT)
    constexpr int F4 = 32 * KT / 4;
    for (int i = tid; i < F4; i += 256) {
      int r = i / (KT / 4);
      int k4 = (i % (KT / 4)) << 2;
      float4 av = *(const float4*)(A + (size_t)(row0 + r) * K + kt + k4);
      if (BN_PRO) {
        float4 sc = *(const float4*)(scale + kt + k4);
        float4 sh = *(const float4*)(shift + kt + k4);
        av.x = fmaxf(av.x * sc.x + sh.x, 0.f);
        av.y = fmaxf(av.y * sc.y + sh.y, 0.f);
        av.z = fmaxf(av.z * sc.z + sh.z, 0.f);
        av.w = fmaxf(av.w * sc.w + sh.w, 0.f);
      }
      *(float4*)&Al[r][k4] = av;
    }
    __syncthreads();
#pragma unroll
    for (int k = 0; k < KT; k++) {
      float4 w4 = *(float4*)&Wl[k][c];
#pragma unroll
      for (int i = 0; i < 4; i++) {
        float a = Al[rg * 4 + i][k];
        acc[i].x += a * w4.x;
        acc[i].y += a * w4.y;
        acc[i].z += a * w4.z;
        acc[i].w += a * w4.w;
      }
    }
    __syncthreads();
  }

  float4 bv = *(const float4*)(bias + c);
#pragma unroll
  for (int i = 0; i < 4; i++) {
    acc[i].x += bv.x;
    acc[i].y += bv.y;
    acc[i].z += bv.z;
    acc[i].w += bv.w;
  }

  if (STATS) {
    float4 s = make_float4(0.f, 0.f, 0.f, 0.f);
    float4 q = make_float4(0.f, 0.f, 0.f, 0.f);
#pragma unroll
    for (int i = 0; i < 4; i++) {
      s.x += acc[i].x; s.y += acc[i].y; s.z += acc[i].z; s.w += acc[i].w;
      q.x += acc[i].x * acc[i].x; q.y += acc[i].y * acc[i].y;
      q.z += acc[i].z * acc[i].z; q.w += acc[i].w * acc[i].w;
    }
    *(float4*)&red[rg][0][c] = s;
    *(float4*)&red[rg][1][c] = q;
  }

#pragma unroll
  for (int i = 0; i < 4; i++) {
    float4 o = acc[i];
    if (RELU) {
      o.x = fmaxf(o.x, 0.f); o.y = fmaxf(o.y, 0.f);
      o.z = fmaxf(o.z, 0.f); o.w = fmaxf(o.w, 0.f);
    }
    *(float4*)(out + (size_t)(row0 + rg * 4 + i) * HID + c) = o;
  }

  if (STATS) {
    __syncthreads();
    if (tid < HID) {
      float s = 0.f, q = 0.f;
#pragma unroll
      for (int r = 0; r < 8; r++) {
        s += red[r][0][tid];
        q += red[r][1][tid];
      }
      atomicAdd(stat + tid, s);
      atomicAdd(stat + HID + tid, q);
    }
  }
}

// ---------------------------------------------------------------------------
// BN finalize: scale = g*rsqrt(var+eps), shift = bt - mu*scale
// ---------------------------------------------------------------------------
__global__ void bn_finalize(const float* __restrict__ stat,
                            const float* __restrict__ g,
                            const float* __restrict__ bt,
                            float* __restrict__ ss) {
  int c = threadIdx.x;  // 128 threads
  float mu = stat[c] / (float)N_NODES;
  float var = stat[HID + c] / (float)N_NODES - mu * mu;
  float sc = g[c] * rsqrtf(var + BN_EPS);
  ss[c] = sc;
  ss[HID + c] = bt[c] - mu * sc;
}

// ---------------------------------------------------------------------------
// Batch pooling (batch is sorted): streaming segment sum, flush on change.
// ---------------------------------------------------------------------------
__global__ __launch_bounds__(128) void pool_kernel(
    const float* __restrict__ x, const int* __restrict__ batch,
    float* __restrict__ pooled) {
  int c = threadIdx.x;
  int r0 = blockIdx.x * 160;
  int r1 = r0 + 160;
  if (r1 > N_NODES) r1 = N_NODES;
  float acc = 0.f;
  int cur = batch[r0];
  for (int r = r0; r < r1; r++) {
    int b = batch[r];
    if (b != cur) {
      atomicAdd(pooled + cur * HID + c, acc);
      acc = 0.f;
      cur = b;
    }
    acc += x[(size_t)r * HID + c];
  }
  atomicAdd(pooled + cur * HID + c, acc);
}

// ---------------------------------------------------------------------------
// Final MLP: out[b,:] = relu(pooled[b]@Wf1+bf1) @ Wf2 + bf2
// ---------------------------------------------------------------------------
__global__ __launch_bounds__(128) void final_mlp(
    const float* __restrict__ pooled, const float* __restrict__ Wf1,
    const float* __restrict__ bf1, const float* __restrict__ Wf2,
    const float* __restrict__ bf2, float* __restrict__ out) {
  __shared__ float pr[HID];
  __shared__ float h[HID];
  int b = blockIdx.x, c = threadIdx.x;
  pr[c] = pooled[b * HID + c];
  __syncthreads();
  float acc = bf1[c];
  for (int k = 0; k < HID; k++) acc += pr[k] * Wf1[k * HID + c];
  h[c] = fmaxf(acc, 0.f);
  __syncthreads();
  if (c < 8) {
    float o = bf2[c];
    for (int k = 0; k < HID; k++) o += h[k] * Wf2[k * 8 + c];
    out[b * 8 + c] = o;
  }
}

// ---------------------------------------------------------------------------
extern "C" void kernel_launch(void* const* d_in, const int* in_sizes, int n_in,
                              void* d_out, int out_size, void* d_ws,
                              size_t ws_size, hipStream_t stream) {
  const float* x_in = (const float*)d_in[0];
  const int* ei = (const int*)d_in[1];
  const float* ea = (const float*)d_in[2];
  const int* batch = (const int*)d_in[3];
  // per-layer params: base index 5 + 8*l
  const float* We[3], *be[3], *W1[3], *b1[3], *g[3], *bt[3], *W2[3], *b2[3];
  for (int l = 0; l < 3; l++) {
    int i0 = 5 + 8 * l;
    We[l] = (const float*)d_in[i0 + 0];
    be[l] = (const float*)d_in[i0 + 1];
    W1[l] = (const float*)d_in[i0 + 2];
    b1[l] = (const float*)d_in[i0 + 3];
    g[l] = (const float*)d_in[i0 + 4];
    bt[l] = (const float*)d_in[i0 + 5];
    W2[l] = (const float*)d_in[i0 + 6];
    b2[l] = (const float*)d_in[i0 + 7];
  }
  const float* Wf1 = (const float*)d_in[29];
  const float* bf1 = (const float*)d_in[30];
  const float* Wf2 = (const float*)d_in[31];
  const float* bf2 = (const float*)d_in[32];
  float* out = (float*)d_out;

  const size_t NH = (size_t)N_NODES * HID;
  float* ws = (float*)d_ws;
  float* xbuf = ws;            // [N,128]
  float* aggr = ws + NH;       // [N,128] (layer0 uses first N*16)
  float* hpre = ws + 2 * NH;   // [N,128]
  float* stat = ws + 3 * NH;   // [256]
  float* ss = stat + 256;      // [256] scale|shift
  float* pooled = ss + 256;    // [64,128]

  // ---------------- Layer 0 (d = 16) ----------------
  hipMemcpyAsync(aggr, x_in, (size_t)N_NODES * F_IN * sizeof(float),
                 hipMemcpyDeviceToDevice, stream);
  hipLaunchKernelGGL(edge_msg16, dim3((N_EDGES * 4 + 255) / 256), dim3(256), 0,
                     stream, x_in, ei, ea, We[0], be[0], aggr);
  hipMemsetAsync(stat, 0, 256 * sizeof(float), stream);
  hipLaunchKernelGGL((gemm_fused<16, false, true, false>), dim3(N_NODES / 32),
                     dim3(256), 0, stream, aggr, W1[0], b1[0], nullptr, nullptr,
                     hpre, stat);
  hipLaunchKernelGGL(bn_finalize, dim3(1), dim3(128), 0, stream, stat, g[0],
                     bt[0], ss);
  hipLaunchKernelGGL((gemm_fused<128, true, false, true>), dim3(N_NODES / 32),
                     dim3(256), 0, stream, hpre, W2[0], b2[0], ss, ss + HID,
                     xbuf, nullptr);

  // ---------------- Layers 1, 2 (d = 128) ----------------
  for (int l = 1; l < 3; l++) {
    hipMemcpyAsync(aggr, xbuf, NH * sizeof(float), hipMemcpyDeviceToDevice,
                   stream);
    hipLaunchKernelGGL(edge_msg128, dim3(N_EDGES * 32 / 256), dim3(256), 0,
                       stream, xbuf, ei, ea, We[l], be[l], aggr);
    hipMemsetAsync(stat, 0, 256 * sizeof(float), stream);
    hipLaunchKernelGGL((gemm_fused<128, false, true, false>),
                       dim3(N_NODES / 32), dim3(256), 0, stream, aggr, W1[l],
                       b1[l], nullptr, nullptr, hpre, stat);
    hipLaunchKernelGGL(bn_finalize, dim3(1), dim3(128), 0, stream, stat, g[l],
                       bt[l], ss);
    hipLaunchKernelGGL((gemm_fused<128, true, false, true>), dim3(N_NODES / 32),
                       dim3(256), 0, stream, hpre, W2[l], b2[l], ss, ss + HID,
                       xbuf, nullptr);
  }

  // ---------------- Pool + final MLP ----------------
  hipMemsetAsync(pooled, 0, (size_t)NB * HID * sizeof(float), stream);
  hipLaunchKernelGGL(pool_kernel, dim3(N_NODES / 160), dim3(128), 0, stream,
                     xbuf, batch, pooled);
  hipLaunchKernelGGL(final_mlp, dim3(NB), dim3(128), 0, stream, pooled, Wf1,
                     bf1, Wf2, bf2, out);
}

// Round 2
// 719.996 us; speedup vs baseline: 3.7150x; 3.7150x over previous
//
#include <hip/hip_runtime.h>
#include <hip/hip_bf16.h>

#define N_NODES 40000
#define N_EDGES 640000
#define HID 128
#define NB 64
#define F_IN 16
#define BN_EPS 1e-5f

// ---------------------------------------------------------------------------
// CSR build: histogram of dst degrees
// ---------------------------------------------------------------------------
__global__ __launch_bounds__(256) void hist_kernel(const int* __restrict__ ei,
                                                   int* __restrict__ deg) {
  int e = blockIdx.x * 256 + threadIdx.x;
  if (e < N_EDGES) atomicAdd(&deg[ei[N_EDGES + e]], 1);
}

// ---------------------------------------------------------------------------
// Single-block exclusive scan of deg[N] -> offs[N+1], cursor[N]=offs[N]
// ---------------------------------------------------------------------------
__global__ __launch_bounds__(1024) void scan_kernel(const int* __restrict__ deg,
                                                    int* __restrict__ offs,
                                                    int* __restrict__ cursor) {
  __shared__ int part[1024];
  int t = threadIdx.x;
  const int CH = 40;  // 1024*40 >= 40000
  int base = t * CH;
  int s = 0;
  for (int k = 0; k < CH; k++) {
    int idx = base + k;
    if (idx < N_NODES) s += deg[idx];
  }
  part[t] = s;
  __syncthreads();
  for (int off = 1; off < 1024; off <<= 1) {
    int v = part[t];
    int u = (t >= off) ? part[t - off] : 0;
    __syncthreads();
    part[t] = v + u;
    __syncthreads();
  }
  int run = (t == 0) ? 0 : part[t - 1];
  for (int k = 0; k < CH; k++) {
    int idx = base + k;
    if (idx < N_NODES) {
      offs[idx] = run;
      cursor[idx] = run;
      run += deg[idx];
    }
  }
  if (t == 1023) offs[N_NODES] = part[1023];
}

// ---------------------------------------------------------------------------
// Scatter edges into dst-sorted lists: elsrc[pos]=src, elea[pos]=(a0,a1)
// ---------------------------------------------------------------------------
__global__ __launch_bounds__(256) void scatter_kernel(
    const int* __restrict__ ei, const float* __restrict__ ea,
    int* __restrict__ cursor, int* __restrict__ elsrc,
    float2* __restrict__ elea) {
  int e = blockIdx.x * 256 + threadIdx.x;
  if (e >= N_EDGES) return;
  int d = ei[N_EDGES + e];
  int pos = atomicAdd(&cursor[d], 1);
  elsrc[pos] = ei[e];
  elea[pos] = make_float2(ea[2 * e], ea[2 * e + 1]);
}

// ---------------------------------------------------------------------------
// Aggregation d=128: out[i,:] = x[i,:] + sum_j relu(x[src_j,:] + ea_j@We + be)
// One block (128 threads) per node, thread c owns feature c. No atomics.
// ---------------------------------------------------------------------------
__global__ __launch_bounds__(128) void aggregate128(
    const float* __restrict__ x, const int* __restrict__ offs,
    const int* __restrict__ elsrc, const float2* __restrict__ elea,
    const float* __restrict__ We, const float* __restrict__ be,
    float* __restrict__ out) {
  int i = blockIdx.x;
  int c = threadIdx.x;
  float we0 = We[c], we1 = We[HID + c], bec = be[c];
  float acc = x[(size_t)i * HID + c];
  int s0 = offs[i], s1 = offs[i + 1];
  for (int j = s0; j < s1; j++) {
    int s = elsrc[j];  // block-uniform -> scalar load
    float2 a = elea[j];
    acc += fmaxf(x[(size_t)s * HID + c] + a.x * we0 + a.y * we1 + bec, 0.f);
  }
  out[(size_t)i * HID + c] = acc;
}

// ---------------------------------------------------------------------------
// Aggregation d=16: 8 nodes per 128-thread block, 16 threads per node.
// ---------------------------------------------------------------------------
__global__ __launch_bounds__(128) void aggregate16(
    const float* __restrict__ x, const int* __restrict__ offs,
    const int* __restrict__ elsrc, const float2* __restrict__ elea,
    const float* __restrict__ We, const float* __restrict__ be,
    float* __restrict__ out) {
  int tid = threadIdx.x;
  int i = blockIdx.x * 8 + (tid >> 4);
  int c = tid & 15;
  float we0 = We[c], we1 = We[F_IN + c], bec = be[c];
  float acc = x[i * F_IN + c];
  int s0 = offs[i], s1 = offs[i + 1];
  for (int j = s0; j < s1; j++) {
    int s = elsrc[j];
    float2 a = elea[j];
    acc += fmaxf(x[s * F_IN + c] + a.x * we0 + a.y * we1 + bec, 0.f);
  }
  out[i * F_IN + c] = acc;
}

// ---------------------------------------------------------------------------
// Tiled f32 GEMM: out[N,128] = A[N,K] @ W[K,128] + bias
//   BN_PRO: A element passed through relu(a*scale[k]+shift[k]) at staging.
//   STATS : accumulate per-column sum/sumsq of out (pre-relu) into stat[256].
//   RELU  : relu on output.
// Block: 256 threads, 32 rows. In-place (out==A) safe for K=128: each block
// reads only its own 32 rows, all reads precede its writes.
// ---------------------------------------------------------------------------
template <int K, bool BN_PRO, bool STATS, bool RELU>
__global__ __launch_bounds__(256) void gemm_fused(
    const float* __restrict__ A, const float* __restrict__ W,
    const float* __restrict__ bias, const float* __restrict__ scale,
    const float* __restrict__ shift, float* __restrict__ out,
    float* __restrict__ stat) {
  constexpr int KT = (K < 32) ? K : 32;
  __shared__ float Wl[KT][HID];
  __shared__ float Al[32][KT];
  __shared__ float red[8][2][HID];

  int tid = threadIdx.x;
  int cg = tid & 31;
  int rg = tid >> 5;
  int c = cg << 2;
  int row0 = blockIdx.x * 32;

  float4 acc[4];
#pragma unroll
  for (int i = 0; i < 4; i++) acc[i] = make_float4(0.f, 0.f, 0.f, 0.f);

  for (int kt = 0; kt < K; kt += KT) {
    for (int i = tid; i < KT * (HID / 4); i += 256) {
      int k = i >> 5;
      int cc = (i & 31) << 2;
      *(float4*)&Wl[k][cc] = *(const float4*)(W + (kt + k) * HID + cc);
    }
    constexpr int F4 = 32 * KT / 4;
    for (int i = tid; i < F4; i += 256) {
      int r = i / (KT / 4);
      int k4 = (i % (KT / 4)) << 2;
      float4 av = *(const float4*)(A + (size_t)(row0 + r) * K + kt + k4);
      if (BN_PRO) {
        float4 sc = *(const float4*)(scale + kt + k4);
        float4 sh = *(const float4*)(shift + kt + k4);
        av.x = fmaxf(av.x * sc.x + sh.x, 0.f);
        av.y = fmaxf(av.y * sc.y + sh.y, 0.f);
        av.z = fmaxf(av.z * sc.z + sh.z, 0.f);
        av.w = fmaxf(av.w * sc.w + sh.w, 0.f);
      }
      *(float4*)&Al[r][k4] = av;
    }
    __syncthreads();
#pragma unroll
    for (int k = 0; k < KT; k++) {
      float4 w4 = *(float4*)&Wl[k][c];
#pragma unroll
      for (int i = 0; i < 4; i++) {
        float a = Al[rg * 4 + i][k];
        acc[i].x += a * w4.x;
        acc[i].y += a * w4.y;
        acc[i].z += a * w4.z;
        acc[i].w += a * w4.w;
      }
    }
    __syncthreads();
  }

  float4 bv = *(const float4*)(bias + c);
#pragma unroll
  for (int i = 0; i < 4; i++) {
    acc[i].x += bv.x;
    acc[i].y += bv.y;
    acc[i].z += bv.z;
    acc[i].w += bv.w;
  }

  if (STATS) {
    float4 s = make_float4(0.f, 0.f, 0.f, 0.f);
    float4 q = make_float4(0.f, 0.f, 0.f, 0.f);
#pragma unroll
    for (int i = 0; i < 4; i++) {
      s.x += acc[i].x; s.y += acc[i].y; s.z += acc[i].z; s.w += acc[i].w;
      q.x += acc[i].x * acc[i].x; q.y += acc[i].y * acc[i].y;
      q.z += acc[i].z * acc[i].z; q.w += acc[i].w * acc[i].w;
    }
    *(float4*)&red[rg][0][c] = s;
    *(float4*)&red[rg][1][c] = q;
  }

#pragma unroll
  for (int i = 0; i < 4; i++) {
    float4 o = acc[i];
    if (RELU) {
      o.x = fmaxf(o.x, 0.f); o.y = fmaxf(o.y, 0.f);
      o.z = fmaxf(o.z, 0.f); o.w = fmaxf(o.w, 0.f);
    }
    *(float4*)(out + (size_t)(row0 + rg * 4 + i) * HID + c) = o;
  }

  if (STATS) {
    __syncthreads();
    if (tid < HID) {
      float s = 0.f, q = 0.f;
#pragma unroll
      for (int r = 0; r < 8; r++) {
        s += red[r][0][tid];
        q += red[r][1][tid];
      }
      atomicAdd(stat + tid, s);
      atomicAdd(stat + HID + tid, q);
    }
  }
}

// ---------------------------------------------------------------------------
__global__ void bn_finalize(const float* __restrict__ stat,
                            const float* __restrict__ g,
                            const float* __restrict__ bt,
                            float* __restrict__ ss) {
  int c = threadIdx.x;  // 128 threads
  float mu = stat[c] / (float)N_NODES;
  float var = stat[HID + c] / (float)N_NODES - mu * mu;
  float sc = g[c] * rsqrtf(var + BN_EPS);
  ss[c] = sc;
  ss[HID + c] = bt[c] - mu * sc;
}

// ---------------------------------------------------------------------------
__global__ __launch_bounds__(128) void pool_kernel(
    const float* __restrict__ x, const int* __restrict__ batch,
    float* __restrict__ pooled) {
  int c = threadIdx.x;
  int r0 = blockIdx.x * 160;
  int r1 = r0 + 160;
  if (r1 > N_NODES) r1 = N_NODES;
  float acc = 0.f;
  int cur = batch[r0];
  for (int r = r0; r < r1; r++) {
    int b = batch[r];
    if (b != cur) {
      atomicAdd(pooled + cur * HID + c, acc);
      acc = 0.f;
      cur = b;
    }
    acc += x[(size_t)r * HID + c];
  }
  atomicAdd(pooled + cur * HID + c, acc);
}

// ---------------------------------------------------------------------------
__global__ __launch_bounds__(128) void final_mlp(
    const float* __restrict__ pooled, const float* __restrict__ Wf1,
    const float* __restrict__ bf1, const float* __restrict__ Wf2,
    const float* __restrict__ bf2, float* __restrict__ out) {
  __shared__ float pr[HID];
  __shared__ float h[HID];
  int b = blockIdx.x, c = threadIdx.x;
  pr[c] = pooled[b * HID + c];
  __syncthreads();
  float acc = bf1[c];
  for (int k = 0; k < HID; k++) acc += pr[k] * Wf1[k * HID + c];
  h[c] = fmaxf(acc, 0.f);
  __syncthreads();
  if (c < 8) {
    float o = bf2[c];
    for (int k = 0; k < HID; k++) o += h[k] * Wf2[k * 8 + c];
    out[b * 8 + c] = o;
  }
}

// ---------------------------------------------------------------------------
extern "C" void kernel_launch(void* const* d_in, const int* in_sizes, int n_in,
                              void* d_out, int out_size, void* d_ws,
                              size_t ws_size, hipStream_t stream) {
  const float* x_in = (const float*)d_in[0];
  const int* ei = (const int*)d_in[1];
  const float* ea = (const float*)d_in[2];
  const int* batch = (const int*)d_in[3];
  const float* We[3], *be[3], *W1[3], *b1[3], *g[3], *bt[3], *W2[3], *b2[3];
  for (int l = 0; l < 3; l++) {
    int i0 = 5 + 8 * l;
    We[l] = (const float*)d_in[i0 + 0];
    be[l] = (const float*)d_in[i0 + 1];
    W1[l] = (const float*)d_in[i0 + 2];
    b1[l] = (const float*)d_in[i0 + 3];
    g[l] = (const float*)d_in[i0 + 4];
    bt[l] = (const float*)d_in[i0 + 5];
    W2[l] = (const float*)d_in[i0 + 6];
    b2[l] = (const float*)d_in[i0 + 7];
  }
  const float* Wf1 = (const float*)d_in[29];
  const float* bf1 = (const float*)d_in[30];
  const float* Wf2 = (const float*)d_in[31];
  const float* bf2 = (const float*)d_in[32];
  float* out = (float*)d_out;

  const size_t NH = (size_t)N_NODES * HID;
  float* ws = (float*)d_ws;
  float* buf0 = ws;                 // [N,128]
  float* buf1 = ws + NH;            // [N,128]
  float* stat = ws + 2 * NH;        // [256]
  float* ss = stat + 256;           // [256]
  float* pooled = ss + 256;         // [64,128]
  int* deg = (int*)(pooled + NB * HID);  // [40000]
  int* offs = deg + N_NODES;             // [40002] (padded for alignment)
  int* cursor = offs + N_NODES + 2;      // [40000]
  int* elsrc = cursor + N_NODES;         // [E]
  float2* elea = (float2*)(elsrc + N_EDGES);  // [E] (8B-aligned by layout)

  // ---------------- CSR build (dst-sorted edge list), once per launch ------
  hipMemsetAsync(deg, 0, N_NODES * sizeof(int), stream);
  hipLaunchKernelGGL(hist_kernel, dim3((N_EDGES + 255) / 256), dim3(256), 0,
                     stream, ei, deg);
  hipLaunchKernelGGL(scan_kernel, dim3(1), dim3(1024), 0, stream, deg, offs,
                     cursor);
  hipLaunchKernelGGL(scatter_kernel, dim3((N_EDGES + 255) / 256), dim3(256), 0,
                     stream, ei, ea, cursor, elsrc, elea);

  // ---------------- Layer 0 (d = 16) ----------------
  hipLaunchKernelGGL(aggregate16, dim3(N_NODES / 8), dim3(128), 0, stream,
                     x_in, offs, elsrc, elea, We[0], be[0], buf1);
  hipMemsetAsync(stat, 0, 256 * sizeof(float), stream);
  hipLaunchKernelGGL((gemm_fused<16, false, true, false>), dim3(N_NODES / 32),
                     dim3(256), 0, stream, buf1, W1[0], b1[0], nullptr, nullptr,
                     buf0, stat);
  hipLaunchKernelGGL(bn_finalize, dim3(1), dim3(128), 0, stream, stat, g[0],
                     bt[0], ss);
  hipLaunchKernelGGL((gemm_fused<128, true, false, true>), dim3(N_NODES / 32),
                     dim3(256), 0, stream, buf0, W2[0], b2[0], ss, ss + HID,
                     buf1, nullptr);

  // ---------------- Layers 1, 2 (d = 128) ----------------
  for (int l = 1; l < 3; l++) {
    hipLaunchKernelGGL(aggregate128, dim3(N_NODES), dim3(128), 0, stream,
                       buf1, offs, elsrc, elea, We[l], be[l], buf0);
    hipMemsetAsync(stat, 0, 256 * sizeof(float), stream);
    hipLaunchKernelGGL((gemm_fused<128, false, true, false>),
                       dim3(N_NODES / 32), dim3(256), 0, stream, buf0, W1[l],
                       b1[l], nullptr, nullptr, buf0, stat);
    hipLaunchKernelGGL(bn_finalize, dim3(1), dim3(128), 0, stream, stat, g[l],
                       bt[l], ss);
    hipLaunchKernelGGL((gemm_fused<128, true, false, true>), dim3(N_NODES / 32),
                       dim3(256), 0, stream, buf0, W2[l], b2[l], ss, ss + HID,
                       buf1, nullptr);
  }

  // ---------------- Pool + final MLP ----------------
  hipMemsetAsync(pooled, 0, (size_t)NB * HID * sizeof(float), stream);
  hipLaunchKernelGGL(pool_kernel, dim3(N_NODES / 160), dim3(128), 0, stream,
                     buf1, batch, pooled);
  hipLaunchKernelGGL(final_mlp, dim3(NB), dim3(128), 0, stream, pooled, Wf1,
                     bf1, Wf2, bf2, out);
}

// Round 3
// 622.992 us; speedup vs baseline: 4.2934x; 1.1557x over previous
//
#include <hip/hip_runtime.h>
#include <hip/hip_bf16.h>

#define N_NODES 40000
#define N_EDGES 640000
#define HID 128
#define NB 64
#define F_IN 16
#define BN_EPS 1e-5f
#define SCAN_NBLK ((N_NODES + 255) / 256)  // 157

// ---------------------------------------------------------------------------
// CSR build: histogram of dst degrees
// ---------------------------------------------------------------------------
__global__ __launch_bounds__(256) void hist_kernel(const int* __restrict__ ei,
                                                   int* __restrict__ deg) {
  int e = blockIdx.x * 256 + threadIdx.x;
  if (e < N_EDGES) atomicAdd(&deg[ei[N_EDGES + e]], 1);
}

// ---------------------------------------------------------------------------
// 3-phase hierarchical exclusive scan of deg[N] -> offs, cursor
// ---------------------------------------------------------------------------
__global__ __launch_bounds__(256) void scan1(const int* __restrict__ deg,
                                             int* __restrict__ offs,
                                             int* __restrict__ bsum) {
  __shared__ int sh[256];
  int t = threadIdx.x;
  int i = blockIdx.x * 256 + t;
  int v = (i < N_NODES) ? deg[i] : 0;
  sh[t] = v;
  __syncthreads();
#pragma unroll
  for (int off = 1; off < 256; off <<= 1) {
    int u = (t >= off) ? sh[t - off] : 0;
    __syncthreads();
    sh[t] += u;
    __syncthreads();
  }
  if (i < N_NODES) offs[i] = sh[t] - v;  // local exclusive
  if (t == 255) bsum[blockIdx.x] = sh[255];
}

__global__ __launch_bounds__(256) void scan2(int* __restrict__ bsum) {
  __shared__ int sh[256];
  int t = threadIdx.x;
  int v = (t < SCAN_NBLK) ? bsum[t] : 0;
  sh[t] = v;
  __syncthreads();
#pragma unroll
  for (int off = 1; off < 256; off <<= 1) {
    int u = (t >= off) ? sh[t - off] : 0;
    __syncthreads();
    sh[t] += u;
    __syncthreads();
  }
  if (t < SCAN_NBLK) bsum[t] = sh[t] - v;  // exclusive block offsets
}

__global__ __launch_bounds__(256) void scan3(const int* __restrict__ bsum,
                                             int* __restrict__ offs,
                                             int* __restrict__ cursor) {
  int i = blockIdx.x * 256 + threadIdx.x;
  if (i < N_NODES) {
    int o = offs[i] + bsum[blockIdx.x];
    offs[i] = o;
    cursor[i] = o;
  }
  if (i == 0) offs[N_NODES] = N_EDGES;
}

// ---------------------------------------------------------------------------
// Scatter edges into dst-sorted lists: elsrc[pos]=src, elea[pos]=(a0,a1)
// ---------------------------------------------------------------------------
__global__ __launch_bounds__(256) void scatter_kernel(
    const int* __restrict__ ei, const float* __restrict__ ea,
    int* __restrict__ cursor, int* __restrict__ elsrc,
    float2* __restrict__ elea) {
  int e = blockIdx.x * 256 + threadIdx.x;
  if (e >= N_EDGES) return;
  int d = ei[N_EDGES + e];
  int pos = atomicAdd(&cursor[d], 1);
  elsrc[pos] = ei[e];
  elea[pos] = make_float2(ea[2 * e], ea[2 * e + 1]);
}

// ---------------------------------------------------------------------------
// Aggregation d=128: out[i,:] = x[i,:] + sum_j relu(x[src_j,:] + ea_j@We + be)
// One block (128 threads) per node, thread c owns feature c. No atomics.
// ---------------------------------------------------------------------------
__global__ __launch_bounds__(128) void aggregate128(
    const float* __restrict__ x, const int* __restrict__ offs,
    const int* __restrict__ elsrc, const float2* __restrict__ elea,
    const float* __restrict__ We, const float* __restrict__ be,
    float* __restrict__ out) {
  int i = blockIdx.x;
  int c = threadIdx.x;
  float we0 = We[c], we1 = We[HID + c], bec = be[c];
  float acc = x[(size_t)i * HID + c];
  int s0 = offs[i], s1 = offs[i + 1];
  for (int j = s0; j < s1; j++) {
    int s = elsrc[j];  // block-uniform -> scalar load
    float2 a = elea[j];
    acc += fmaxf(x[(size_t)s * HID + c] + a.x * we0 + a.y * we1 + bec, 0.f);
  }
  out[(size_t)i * HID + c] = acc;
}

// ---------------------------------------------------------------------------
// Aggregation d=16: 8 nodes per 128-thread block, 16 threads per node.
// ---------------------------------------------------------------------------
__global__ __launch_bounds__(128) void aggregate16(
    const float* __restrict__ x, const int* __restrict__ offs,
    const int* __restrict__ elsrc, const float2* __restrict__ elea,
    const float* __restrict__ We, const float* __restrict__ be,
    float* __restrict__ out) {
  int tid = threadIdx.x;
  int i = blockIdx.x * 8 + (tid >> 4);
  int c = tid & 15;
  float we0 = We[c], we1 = We[F_IN + c], bec = be[c];
  float acc = x[i * F_IN + c];
  int s0 = offs[i], s1 = offs[i + 1];
  for (int j = s0; j < s1; j++) {
    int s = elsrc[j];
    float2 a = elea[j];
    acc += fmaxf(x[s * F_IN + c] + a.x * we0 + a.y * we1 + bec, 0.f);
  }
  out[i * F_IN + c] = acc;
}

// ---------------------------------------------------------------------------
// Tiled f32 GEMM: out[N,128] = A[N,K] @ W[K,128] + bias
//   BN_PRO: A element passed through relu(a*scale[k]+shift[k]) at staging.
//   STATS : accumulate per-column sum/sumsq of out (pre-relu) into stat[256].
//   RELU  : relu on output.
// Block: 256 threads, 32 rows. In-place (out==A) safe for K=128: each block
// reads only its own 32 rows, all reads precede its writes.
// ---------------------------------------------------------------------------
template <int K, bool BN_PRO, bool STATS, bool RELU>
__global__ __launch_bounds__(256) void gemm_fused(
    const float* __restrict__ A, const float* __restrict__ W,
    const float* __restrict__ bias, const float* __restrict__ scale,
    const float* __restrict__ shift, float* __restrict__ out,
    float* __restrict__ stat) {
  constexpr int KT = (K < 32) ? K : 32;
  __shared__ float Wl[KT][HID];
  __shared__ float Al[32][KT];
  __shared__ float red[8][2][HID];

  int tid = threadIdx.x;
  int cg = tid & 31;
  int rg = tid >> 5;
  int c = cg << 2;
  int row0 = blockIdx.x * 32;

  float4 acc[4];
#pragma unroll
  for (int i = 0; i < 4; i++) acc[i] = make_float4(0.f, 0.f, 0.f, 0.f);

  for (int kt = 0; kt < K; kt += KT) {
    for (int i = tid; i < KT * (HID / 4); i += 256) {
      int k = i >> 5;
      int cc = (i & 31) << 2;
      *(float4*)&Wl[k][cc] = *(const float4*)(W + (kt + k) * HID + cc);
    }
    constexpr int F4 = 32 * KT / 4;
    for (int i = tid; i < F4; i += 256) {
      int r = i / (KT / 4);
      int k4 = (i % (KT / 4)) << 2;
      float4 av = *(const float4*)(A + (size_t)(row0 + r) * K + kt + k4);
      if (BN_PRO) {
        float4 sc = *(const float4*)(scale + kt + k4);
        float4 sh = *(const float4*)(shift + kt + k4);
        av.x = fmaxf(av.x * sc.x + sh.x, 0.f);
        av.y = fmaxf(av.y * sc.y + sh.y, 0.f);
        av.z = fmaxf(av.z * sc.z + sh.z, 0.f);
        av.w = fmaxf(av.w * sc.w + sh.w, 0.f);
      }
      *(float4*)&Al[r][k4] = av;
    }
    __syncthreads();
#pragma unroll
    for (int k = 0; k < KT; k++) {
      float4 w4 = *(float4*)&Wl[k][c];
#pragma unroll
      for (int i = 0; i < 4; i++) {
        float a = Al[rg * 4 + i][k];
        acc[i].x += a * w4.x;
        acc[i].y += a * w4.y;
        acc[i].z += a * w4.z;
        acc[i].w += a * w4.w;
      }
    }
    __syncthreads();
  }

  float4 bv = *(const float4*)(bias + c);
#pragma unroll
  for (int i = 0; i < 4; i++) {
    acc[i].x += bv.x;
    acc[i].y += bv.y;
    acc[i].z += bv.z;
    acc[i].w += bv.w;
  }

  if (STATS) {
    float4 s = make_float4(0.f, 0.f, 0.f, 0.f);
    float4 q = make_float4(0.f, 0.f, 0.f, 0.f);
#pragma unroll
    for (int i = 0; i < 4; i++) {
      s.x += acc[i].x; s.y += acc[i].y; s.z += acc[i].z; s.w += acc[i].w;
      q.x += acc[i].x * acc[i].x; q.y += acc[i].y * acc[i].y;
      q.z += acc[i].z * acc[i].z; q.w += acc[i].w * acc[i].w;
    }
    *(float4*)&red[rg][0][c] = s;
    *(float4*)&red[rg][1][c] = q;
  }

#pragma unroll
  for (int i = 0; i < 4; i++) {
    float4 o = acc[i];
    if (RELU) {
      o.x = fmaxf(o.x, 0.f); o.y = fmaxf(o.y, 0.f);
      o.z = fmaxf(o.z, 0.f); o.w = fmaxf(o.w, 0.f);
    }
    *(float4*)(out + (size_t)(row0 + rg * 4 + i) * HID + c) = o;
  }

  if (STATS) {
    __syncthreads();
    if (tid < HID) {
      float s = 0.f, q = 0.f;
#pragma unroll
      for (int r = 0; r < 8; r++) {
        s += red[r][0][tid];
        q += red[r][1][tid];
      }
      atomicAdd(stat + tid, s);
      atomicAdd(stat + HID + tid, q);
    }
  }
}

// ---------------------------------------------------------------------------
__global__ void bn_finalize(const float* __restrict__ stat,
                            const float* __restrict__ g,
                            const float* __restrict__ bt,
                            float* __restrict__ ss) {
  int c = threadIdx.x;  // 128 threads
  float mu = stat[c] / (float)N_NODES;
  float var = stat[HID + c] / (float)N_NODES - mu * mu;
  float sc = g[c] * rsqrtf(var + BN_EPS);
  ss[c] = sc;
  ss[HID + c] = bt[c] - mu * sc;
}

// ---------------------------------------------------------------------------
__global__ __launch_bounds__(128) void pool_kernel(
    const float* __restrict__ x, const int* __restrict__ batch,
    float* __restrict__ pooled) {
  int c = threadIdx.x;
  int r0 = blockIdx.x * 160;
  int r1 = r0 + 160;
  if (r1 > N_NODES) r1 = N_NODES;
  float acc = 0.f;
  int cur = batch[r0];
  for (int r = r0; r < r1; r++) {
    int b = batch[r];
    if (b != cur) {
      atomicAdd(pooled + cur * HID + c, acc);
      acc = 0.f;
      cur = b;
    }
    acc += x[(size_t)r * HID + c];
  }
  atomicAdd(pooled + cur * HID + c, acc);
}

// ---------------------------------------------------------------------------
__global__ __launch_bounds__(128) void final_mlp(
    const float* __restrict__ pooled, const float* __restrict__ Wf1,
    const float* __restrict__ bf1, const float* __restrict__ Wf2,
    const float* __restrict__ bf2, float* __restrict__ out) {
  __shared__ float pr[HID];
  __shared__ float h[HID];
  int b = blockIdx.x, c = threadIdx.x;
  pr[c] = pooled[b * HID + c];
  __syncthreads();
  float acc = bf1[c];
  for (int k = 0; k < HID; k++) acc += pr[k] * Wf1[k * HID + c];
  h[c] = fmaxf(acc, 0.f);
  __syncthreads();
  if (c < 8) {
    float o = bf2[c];
    for (int k = 0; k < HID; k++) o += h[k] * Wf2[k * 8 + c];
    out[b * 8 + c] = o;
  }
}

// ---------------------------------------------------------------------------
extern "C" void kernel_launch(void* const* d_in, const int* in_sizes, int n_in,
                              void* d_out, int out_size, void* d_ws,
                              size_t ws_size, hipStream_t stream) {
  const float* x_in = (const float*)d_in[0];
  const int* ei = (const int*)d_in[1];
  const float* ea = (const float*)d_in[2];
  const int* batch = (const int*)d_in[3];
  const float* We[3], *be[3], *W1[3], *b1[3], *g[3], *bt[3], *W2[3], *b2[3];
  for (int l = 0; l < 3; l++) {
    int i0 = 5 + 8 * l;
    We[l] = (const float*)d_in[i0 + 0];
    be[l] = (const float*)d_in[i0 + 1];
    W1[l] = (const float*)d_in[i0 + 2];
    b1[l] = (const float*)d_in[i0 + 3];
    g[l] = (const float*)d_in[i0 + 4];
    bt[l] = (const float*)d_in[i0 + 5];
    W2[l] = (const float*)d_in[i0 + 6];
    b2[l] = (const float*)d_in[i0 + 7];
  }
  const float* Wf1 = (const float*)d_in[29];
  const float* bf1 = (const float*)d_in[30];
  const float* Wf2 = (const float*)d_in[31];
  const float* bf2 = (const float*)d_in[32];
  float* out = (float*)d_out;

  const size_t NH = (size_t)N_NODES * HID;
  float* ws = (float*)d_ws;
  float* buf0 = ws;                 // [N,128]
  float* buf1 = ws + NH;            // [N,128]
  float* stat = ws + 2 * NH;        // [256]
  float* ss = stat + 256;           // [256]
  float* pooled = ss + 256;         // [64,128]
  int* deg = (int*)(pooled + NB * HID);  // [40000]
  int* offs = deg + N_NODES;             // [40001 pad 2]
  int* cursor = offs + N_NODES + 2;      // [40000]
  int* bsum = cursor + N_NODES;          // [256]
  int* elsrc = bsum + 256;               // [E]
  float2* elea = (float2*)(elsrc + N_EDGES);  // [E]

  // ---------------- CSR build (dst-sorted edge list), once per launch ------
  hipMemsetAsync(deg, 0, N_NODES * sizeof(int), stream);
  hipLaunchKernelGGL(hist_kernel, dim3((N_EDGES + 255) / 256), dim3(256), 0,
                     stream, ei, deg);
  hipLaunchKernelGGL(scan1, dim3(SCAN_NBLK), dim3(256), 0, stream, deg, offs,
                     bsum);
  hipLaunchKernelGGL(scan2, dim3(1), dim3(256), 0, stream, bsum);
  hipLaunchKernelGGL(scan3, dim3(SCAN_NBLK), dim3(256), 0, stream, bsum, offs,
                     cursor);
  hipLaunchKernelGGL(scatter_kernel, dim3((N_EDGES + 255) / 256), dim3(256), 0,
                     stream, ei, ea, cursor, elsrc, elea);

  // ---------------- Layer 0 (d = 16) ----------------
  hipLaunchKernelGGL(aggregate16, dim3(N_NODES / 8), dim3(128), 0, stream,
                     x_in, offs, elsrc, elea, We[0], be[0], buf1);
  hipMemsetAsync(stat, 0, 256 * sizeof(float), stream);
  hipLaunchKernelGGL((gemm_fused<16, false, true, false>), dim3(N_NODES / 32),
                     dim3(256), 0, stream, buf1, W1[0], b1[0], nullptr, nullptr,
                     buf0, stat);
  hipLaunchKernelGGL(bn_finalize, dim3(1), dim3(128), 0, stream, stat, g[0],
                     bt[0], ss);
  hipLaunchKernelGGL((gemm_fused<128, true, false, true>), dim3(N_NODES / 32),
                     dim3(256), 0, stream, buf0, W2[0], b2[0], ss, ss + HID,
                     buf1, nullptr);

  // ---------------- Layers 1, 2 (d = 128) ----------------
  for (int l = 1; l < 3; l++) {
    hipLaunchKernelGGL(aggregate128, dim3(N_NODES), dim3(128), 0, stream,
                       buf1, offs, elsrc, elea, We[l], be[l], buf0);
    hipMemsetAsync(stat, 0, 256 * sizeof(float), stream);
    hipLaunchKernelGGL((gemm_fused<128, false, true, false>),
                       dim3(N_NODES / 32), dim3(256), 0, stream, buf0, W1[l],
                       b1[l], nullptr, nullptr, buf0, stat);
    hipLaunchKernelGGL(bn_finalize, dim3(1), dim3(128), 0, stream, stat, g[l],
                       bt[l], ss);
    hipLaunchKernelGGL((gemm_fused<128, true, false, true>), dim3(N_NODES / 32),
                       dim3(256), 0, stream, buf0, W2[l], b2[l], ss, ss + HID,
                       buf1, nullptr);
  }

  // ---------------- Pool + final MLP ----------------
  hipMemsetAsync(pooled, 0, (size_t)NB * HID * sizeof(float), stream);
  hipLaunchKernelGGL(pool_kernel, dim3(N_NODES / 160), dim3(128), 0, stream,
                     buf1, batch, pooled);
  hipLaunchKernelGGL(final_mlp, dim3(NB), dim3(128), 0, stream, pooled, Wf1,
                     bf1, Wf2, bf2, out);
}

// Round 4
// 574.050 us; speedup vs baseline: 4.6595x; 1.0853x over previous
//
#include <hip/hip_runtime.h>
#include <hip/hip_bf16.h>

#define N_NODES 40000
#define N_EDGES 640000
#define HID 128
#define NB 64
#define F_IN 16
#define BN_EPS 1e-5f
#define SCAN_NBLK ((N_NODES + 255) / 256)  // 157

typedef unsigned short u16;
typedef unsigned int u32;

__device__ __forceinline__ float bf2f(u16 u) {
  u32 v = ((u32)u) << 16;
  return __builtin_bit_cast(float, v);
}
__device__ __forceinline__ u16 f2bf(float f) {
  u32 v = __builtin_bit_cast(u32, f);
  u32 r = 0x7FFFu + ((v >> 16) & 1u);  // round-to-nearest-even
  return (u16)((v + r) >> 16);
}

// ---------------------------------------------------------------------------
// CSR build: histogram of dst degrees
// ---------------------------------------------------------------------------
__global__ __launch_bounds__(256) void hist_kernel(const int* __restrict__ ei,
                                                   int* __restrict__ deg) {
  int e = blockIdx.x * 256 + threadIdx.x;
  if (e < N_EDGES) atomicAdd(&deg[ei[N_EDGES + e]], 1);
}

// ---------------------------------------------------------------------------
// 3-phase hierarchical exclusive scan of deg[N] -> offs, cursor
// ---------------------------------------------------------------------------
__global__ __launch_bounds__(256) void scan1(const int* __restrict__ deg,
                                             int* __restrict__ offs,
                                             int* __restrict__ bsum) {
  __shared__ int sh[256];
  int t = threadIdx.x;
  int i = blockIdx.x * 256 + t;
  int v = (i < N_NODES) ? deg[i] : 0;
  sh[t] = v;
  __syncthreads();
#pragma unroll
  for (int off = 1; off < 256; off <<= 1) {
    int u = (t >= off) ? sh[t - off] : 0;
    __syncthreads();
    sh[t] += u;
    __syncthreads();
  }
  if (i < N_NODES) offs[i] = sh[t] - v;  // local exclusive
  if (t == 255) bsum[blockIdx.x] = sh[255];
}

__global__ __launch_bounds__(256) void scan2(int* __restrict__ bsum) {
  __shared__ int sh[256];
  int t = threadIdx.x;
  int v = (t < SCAN_NBLK) ? bsum[t] : 0;
  sh[t] = v;
  __syncthreads();
#pragma unroll
  for (int off = 1; off < 256; off <<= 1) {
    int u = (t >= off) ? sh[t - off] : 0;
    __syncthreads();
    sh[t] += u;
    __syncthreads();
  }
  if (t < SCAN_NBLK) bsum[t] = sh[t] - v;  // exclusive block offsets
}

__global__ __launch_bounds__(256) void scan3(const int* __restrict__ bsum,
                                             int* __restrict__ offs,
                                             int* __restrict__ cursor) {
  int i = blockIdx.x * 256 + threadIdx.x;
  if (i < N_NODES) {
    int o = offs[i] + bsum[blockIdx.x];
    offs[i] = o;
    cursor[i] = o;
  }
  if (i == 0) offs[N_NODES] = N_EDGES;
}

// ---------------------------------------------------------------------------
// Scatter edges into dst-sorted lists: elsrc[pos]=src, elea[pos]=(a0,a1)
// ---------------------------------------------------------------------------
__global__ __launch_bounds__(256) void scatter_kernel(
    const int* __restrict__ ei, const float* __restrict__ ea,
    int* __restrict__ cursor, int* __restrict__ elsrc,
    float2* __restrict__ elea) {
  int e = blockIdx.x * 256 + threadIdx.x;
  if (e >= N_EDGES) return;
  int d = ei[N_EDGES + e];
  int pos = atomicAdd(&cursor[d], 1);
  elsrc[pos] = ei[e];
  elea[pos] = make_float2(ea[2 * e], ea[2 * e + 1]);
}

// ---------------------------------------------------------------------------
// Aggregation d=128, bf16 x: out[i,:] = x[i,:] + sum_j relu(x[src_j]+ea@We+be)
// One wave (64 threads) per node; lane owns 2 features (ushort2 gather).
// blockIdx-uniform edge loop -> scalar elsrc/elea loads. No atomics.
// ---------------------------------------------------------------------------
__global__ __launch_bounds__(64) void aggregate128_bf16(
    const u16* __restrict__ xb, const int* __restrict__ offs,
    const int* __restrict__ elsrc, const float2* __restrict__ elea,
    const float* __restrict__ We, const float* __restrict__ be,
    float* __restrict__ out) {
  int i = blockIdx.x;
  int c = threadIdx.x * 2;
  float2 we0 = *(const float2*)(We + c);
  float2 we1 = *(const float2*)(We + HID + c);
  float2 bec = *(const float2*)(be + c);
  ushort2 xs = *(const ushort2*)(xb + (size_t)i * HID + c);
  float acc0 = bf2f(xs.x), acc1 = bf2f(xs.y);
  int s0 = offs[i], s1 = offs[i + 1];
  for (int j = s0; j < s1; j++) {
    int s = elsrc[j];
    float2 a = elea[j];
    ushort2 u = *(const ushort2*)(xb + (size_t)s * HID + c);
    acc0 += fmaxf(bf2f(u.x) + a.x * we0.x + a.y * we1.x + bec.x, 0.f);
    acc1 += fmaxf(bf2f(u.y) + a.x * we0.y + a.y * we1.y + bec.y, 0.f);
  }
  *(float2*)(out + (size_t)i * HID + c) = make_float2(acc0, acc1);
}

// ---------------------------------------------------------------------------
// Aggregation d=16 (layer 0, f32 input x): 8 nodes per 128-thread block.
// ---------------------------------------------------------------------------
__global__ __launch_bounds__(128) void aggregate16(
    const float* __restrict__ x, const int* __restrict__ offs,
    const int* __restrict__ elsrc, const float2* __restrict__ elea,
    const float* __restrict__ We, const float* __restrict__ be,
    float* __restrict__ out) {
  int tid = threadIdx.x;
  int i = blockIdx.x * 8 + (tid >> 4);
  int c = tid & 15;
  float we0 = We[c], we1 = We[F_IN + c], bec = be[c];
  float acc = x[i * F_IN + c];
  int s0 = offs[i], s1 = offs[i + 1];
  for (int j = s0; j < s1; j++) {
    int s = elsrc[j];
    float2 a = elea[j];
    acc += fmaxf(x[s * F_IN + c] + a.x * we0 + a.y * we1 + bec, 0.f);
  }
  out[i * F_IN + c] = acc;
}

// ---------------------------------------------------------------------------
// Tiled f32 GEMM: out[N,128] = A[N,K] @ W[K,128] + bias
//   BN_PRO  : A passed through relu(a*scale[k]+shift[k]) at staging.
//   STATS   : accumulate per-column sum/sumsq of out (pre-relu) into stat.
//   RELU    : relu on output.
//   OUT_BF16: output written as bf16 (RNE) instead of f32.
// Block: 256 threads, 32 rows. In-place (out==A) safe only for K=128.
// ---------------------------------------------------------------------------
template <int K, bool BN_PRO, bool STATS, bool RELU, bool OUT_BF16>
__global__ __launch_bounds__(256) void gemm_fused(
    const float* __restrict__ A, const float* __restrict__ W,
    const float* __restrict__ bias, const float* __restrict__ scale,
    const float* __restrict__ shift, void* __restrict__ outv,
    float* __restrict__ stat) {
  constexpr int KT = (K < 32) ? K : 32;
  __shared__ float Wl[KT][HID];
  __shared__ float Al[32][KT];
  __shared__ float red[8][2][HID];

  int tid = threadIdx.x;
  int cg = tid & 31;
  int rg = tid >> 5;
  int c = cg << 2;
  int row0 = blockIdx.x * 32;

  float4 acc[4];
#pragma unroll
  for (int i = 0; i < 4; i++) acc[i] = make_float4(0.f, 0.f, 0.f, 0.f);

  for (int kt = 0; kt < K; kt += KT) {
    for (int i = tid; i < KT * (HID / 4); i += 256) {
      int k = i >> 5;
      int cc = (i & 31) << 2;
      *(float4*)&Wl[k][cc] = *(const float4*)(W + (kt + k) * HID + cc);
    }
    constexpr int F4 = 32 * KT / 4;
    for (int i = tid; i < F4; i += 256) {
      int r = i / (KT / 4);
      int k4 = (i % (KT / 4)) << 2;
      float4 av = *(const float4*)(A + (size_t)(row0 + r) * K + kt + k4);
      if (BN_PRO) {
        float4 sc = *(const float4*)(scale + kt + k4);
        float4 sh = *(const float4*)(shift + kt + k4);
        av.x = fmaxf(av.x * sc.x + sh.x, 0.f);
        av.y = fmaxf(av.y * sc.y + sh.y, 0.f);
        av.z = fmaxf(av.z * sc.z + sh.z, 0.f);
        av.w = fmaxf(av.w * sc.w + sh.w, 0.f);
      }
      *(float4*)&Al[r][k4] = av;
    }
    __syncthreads();
#pragma unroll
    for (int k = 0; k < KT; k++) {
      float4 w4 = *(float4*)&Wl[k][c];
#pragma unroll
      for (int i = 0; i < 4; i++) {
        float a = Al[rg * 4 + i][k];
        acc[i].x += a * w4.x;
        acc[i].y += a * w4.y;
        acc[i].z += a * w4.z;
        acc[i].w += a * w4.w;
      }
    }
    __syncthreads();
  }

  float4 bv = *(const float4*)(bias + c);
#pragma unroll
  for (int i = 0; i < 4; i++) {
    acc[i].x += bv.x;
    acc[i].y += bv.y;
    acc[i].z += bv.z;
    acc[i].w += bv.w;
  }

  if (STATS) {
    float4 s = make_float4(0.f, 0.f, 0.f, 0.f);
    float4 q = make_float4(0.f, 0.f, 0.f, 0.f);
#pragma unroll
    for (int i = 0; i < 4; i++) {
      s.x += acc[i].x; s.y += acc[i].y; s.z += acc[i].z; s.w += acc[i].w;
      q.x += acc[i].x * acc[i].x; q.y += acc[i].y * acc[i].y;
      q.z += acc[i].z * acc[i].z; q.w += acc[i].w * acc[i].w;
    }
    *(float4*)&red[rg][0][c] = s;
    *(float4*)&red[rg][1][c] = q;
  }

#pragma unroll
  for (int i = 0; i < 4; i++) {
    float4 o = acc[i];
    if (RELU) {
      o.x = fmaxf(o.x, 0.f); o.y = fmaxf(o.y, 0.f);
      o.z = fmaxf(o.z, 0.f); o.w = fmaxf(o.w, 0.f);
    }
    if (OUT_BF16) {
      ushort4 o16;
      o16.x = f2bf(o.x); o16.y = f2bf(o.y);
      o16.z = f2bf(o.z); o16.w = f2bf(o.w);
      *(ushort4*)((u16*)outv + (size_t)(row0 + rg * 4 + i) * HID + c) = o16;
    } else {
      *(float4*)((float*)outv + (size_t)(row0 + rg * 4 + i) * HID + c) = o;
    }
  }

  if (STATS) {
    __syncthreads();
    if (tid < HID) {
      float s = 0.f, q = 0.f;
#pragma unroll
      for (int r = 0; r < 8; r++) {
        s += red[r][0][tid];
        q += red[r][1][tid];
      }
      atomicAdd(stat + tid, s);
      atomicAdd(stat + HID + tid, q);
    }
  }
}

// ---------------------------------------------------------------------------
__global__ void bn_finalize(const float* __restrict__ stat,
                            const float* __restrict__ g,
                            const float* __restrict__ bt,
                            float* __restrict__ ss) {
  int c = threadIdx.x;  // 128 threads
  float mu = stat[c] / (float)N_NODES;
  float var = stat[HID + c] / (float)N_NODES - mu * mu;
  float sc = g[c] * rsqrtf(var + BN_EPS);
  ss[c] = sc;
  ss[HID + c] = bt[c] - mu * sc;
}

// ---------------------------------------------------------------------------
// Batch pooling over bf16 x (batch sorted): flush on segment change.
// ---------------------------------------------------------------------------
__global__ __launch_bounds__(128) void pool_kernel(
    const u16* __restrict__ xb, const int* __restrict__ batch,
    float* __restrict__ pooled) {
  int c = threadIdx.x;
  int r0 = blockIdx.x * 160;
  int r1 = r0 + 160;
  if (r1 > N_NODES) r1 = N_NODES;
  float acc = 0.f;
  int cur = batch[r0];
  for (int r = r0; r < r1; r++) {
    int b = batch[r];
    if (b != cur) {
      atomicAdd(pooled + cur * HID + c, acc);
      acc = 0.f;
      cur = b;
    }
    acc += bf2f(xb[(size_t)r * HID + c]);
  }
  atomicAdd(pooled + cur * HID + c, acc);
}

// ---------------------------------------------------------------------------
__global__ __launch_bounds__(128) void final_mlp(
    const float* __restrict__ pooled, const float* __restrict__ Wf1,
    const float* __restrict__ bf1, const float* __restrict__ Wf2,
    const float* __restrict__ bf2, float* __restrict__ out) {
  __shared__ float pr[HID];
  __shared__ float h[HID];
  int b = blockIdx.x, c = threadIdx.x;
  pr[c] = pooled[b * HID + c];
  __syncthreads();
  float acc = bf1[c];
  for (int k = 0; k < HID; k++) acc += pr[k] * Wf1[k * HID + c];
  h[c] = fmaxf(acc, 0.f);
  __syncthreads();
  if (c < 8) {
    float o = bf2[c];
    for (int k = 0; k < HID; k++) o += h[k] * Wf2[k * 8 + c];
    out[b * 8 + c] = o;
  }
}

// ---------------------------------------------------------------------------
extern "C" void kernel_launch(void* const* d_in, const int* in_sizes, int n_in,
                              void* d_out, int out_size, void* d_ws,
                              size_t ws_size, hipStream_t stream) {
  const float* x_in = (const float*)d_in[0];
  const int* ei = (const int*)d_in[1];
  const float* ea = (const float*)d_in[2];
  const int* batch = (const int*)d_in[3];
  const float* We[3], *be[3], *W1[3], *b1[3], *g[3], *bt[3], *W2[3], *b2[3];
  for (int l = 0; l < 3; l++) {
    int i0 = 5 + 8 * l;
    We[l] = (const float*)d_in[i0 + 0];
    be[l] = (const float*)d_in[i0 + 1];
    W1[l] = (const float*)d_in[i0 + 2];
    b1[l] = (const float*)d_in[i0 + 3];
    g[l] = (const float*)d_in[i0 + 4];
    bt[l] = (const float*)d_in[i0 + 5];
    W2[l] = (const float*)d_in[i0 + 6];
    b2[l] = (const float*)d_in[i0 + 7];
  }
  const float* Wf1 = (const float*)d_in[29];
  const float* bf1 = (const float*)d_in[30];
  const float* Wf2 = (const float*)d_in[31];
  const float* bf2 = (const float*)d_in[32];
  float* out = (float*)d_out;

  const size_t NH = (size_t)N_NODES * HID;
  float* ws = (float*)d_ws;
  float* buf0 = ws;                       // [N,128] f32 (aggr / hpre in-place)
  u16* xb = (u16*)(ws + NH);              // [N,128] bf16 layer output
  float* agg16 = ws + NH + NH / 2;        // [N,16] f32 (layer0 aggregation)
  float* stat = agg16 + (size_t)N_NODES * F_IN;  // [256]
  float* ss = stat + 256;                 // [256]
  float* pooled = ss + 256;               // [64,128]
  int* deg = (int*)(pooled + NB * HID);   // [40000]
  int* offs = deg + N_NODES;              // [40001 pad 2]
  int* cursor = offs + N_NODES + 2;       // [40000]
  int* bsum = cursor + N_NODES;           // [256]
  int* elsrc = bsum + 256;                // [E]
  float2* elea = (float2*)(elsrc + N_EDGES);  // [E]

  // ---------------- CSR build (dst-sorted edge list) ----------------
  hipMemsetAsync(deg, 0, N_NODES * sizeof(int), stream);
  hipLaunchKernelGGL(hist_kernel, dim3((N_EDGES + 255) / 256), dim3(256), 0,
                     stream, ei, deg);
  hipLaunchKernelGGL(scan1, dim3(SCAN_NBLK), dim3(256), 0, stream, deg, offs,
                     bsum);
  hipLaunchKernelGGL(scan2, dim3(1), dim3(256), 0, stream, bsum);
  hipLaunchKernelGGL(scan3, dim3(SCAN_NBLK), dim3(256), 0, stream, bsum, offs,
                     cursor);
  hipLaunchKernelGGL(scatter_kernel, dim3((N_EDGES + 255) / 256), dim3(256), 0,
                     stream, ei, ea, cursor, elsrc, elea);

  // ---------------- Layer 0 (d = 16) ----------------
  hipLaunchKernelGGL(aggregate16, dim3(N_NODES / 8), dim3(128), 0, stream,
                     x_in, offs, elsrc, elea, We[0], be[0], agg16);
  hipMemsetAsync(stat, 0, 256 * sizeof(float), stream);
  hipLaunchKernelGGL((gemm_fused<16, false, true, false, false>),
                     dim3(N_NODES / 32), dim3(256), 0, stream, agg16, W1[0],
                     b1[0], nullptr, nullptr, buf0, stat);
  hipLaunchKernelGGL(bn_finalize, dim3(1), dim3(128), 0, stream, stat, g[0],
                     bt[0], ss);
  hipLaunchKernelGGL((gemm_fused<128, true, false, true, true>),
                     dim3(N_NODES / 32), dim3(256), 0, stream, buf0, W2[0],
                     b2[0], ss, ss + HID, xb, nullptr);

  // ---------------- Layers 1, 2 (d = 128) ----------------
  for (int l = 1; l < 3; l++) {
    hipLaunchKernelGGL(aggregate128_bf16, dim3(N_NODES), dim3(64), 0, stream,
                       xb, offs, elsrc, elea, We[l], be[l], buf0);
    hipMemsetAsync(stat, 0, 256 * sizeof(float), stream);
    hipLaunchKernelGGL((gemm_fused<128, false, true, false, false>),
                       dim3(N_NODES / 32), dim3(256), 0, stream, buf0, W1[l],
                       b1[l], nullptr, nullptr, buf0, stat);
    hipLaunchKernelGGL(bn_finalize, dim3(1), dim3(128), 0, stream, stat, g[l],
                       bt[l], ss);
    hipLaunchKernelGGL((gemm_fused<128, true, false, true, true>),
                       dim3(N_NODES / 32), dim3(256), 0, stream, buf0, W2[l],
                       b2[l], ss, ss + HID, xb, nullptr);
  }

  // ---------------- Pool + final MLP ----------------
  hipMemsetAsync(pooled, 0, (size_t)NB * HID * sizeof(float), stream);
  hipLaunchKernelGGL(pool_kernel, dim3(N_NODES / 160), dim3(128), 0, stream,
                     xb, batch, pooled);
  hipLaunchKernelGGL(final_mlp, dim3(NB), dim3(128), 0, stream, pooled, Wf1,
                     bf1, Wf2, bf2, out);
}

// Round 5
// 507.649 us; speedup vs baseline: 5.2689x; 1.1308x over previous
//
#include <hip/hip_runtime.h>
#include <hip/hip_bf16.h>

#define N_NODES 40000
#define N_EDGES 640000
#define HID 128
#define NB 64
#define F_IN 16
#define BN_EPS 1e-5f
#define SCAN_NBLK ((N_NODES + 255) / 256)  // 157
#define NT_ROWS (N_NODES / 16)             // 2500 row-tiles

typedef unsigned short u16;
typedef unsigned int u32;
typedef __attribute__((ext_vector_type(8))) __bf16 bf16x8;
typedef __attribute__((ext_vector_type(8))) unsigned short u16x8;
typedef __attribute__((ext_vector_type(4))) float f32x4;

__device__ __forceinline__ float bf2f(u16 u) {
  u32 v = ((u32)u) << 16;
  return __builtin_bit_cast(float, v);
}
__device__ __forceinline__ u16 f2bf(float f) {
  u32 v = __builtin_bit_cast(u32, f);
  u32 r = 0x7FFFu + ((v >> 16) & 1u);  // round-to-nearest-even
  return (u16)((v + r) >> 16);
}

// ---------------------------------------------------------------------------
// CSR build: histogram of dst degrees
// ---------------------------------------------------------------------------
__global__ __launch_bounds__(256) void hist_kernel(const int* __restrict__ ei,
                                                   int* __restrict__ deg) {
  int e = blockIdx.x * 256 + threadIdx.x;
  if (e < N_EDGES) atomicAdd(&deg[ei[N_EDGES + e]], 1);
}

// ---------------------------------------------------------------------------
// 3-phase hierarchical exclusive scan of deg[N] -> offs, cursor
// ---------------------------------------------------------------------------
__global__ __launch_bounds__(256) void scan1(const int* __restrict__ deg,
                                             int* __restrict__ offs,
                                             int* __restrict__ bsum) {
  __shared__ int sh[256];
  int t = threadIdx.x;
  int i = blockIdx.x * 256 + t;
  int v = (i < N_NODES) ? deg[i] : 0;
  sh[t] = v;
  __syncthreads();
#pragma unroll
  for (int off = 1; off < 256; off <<= 1) {
    int u = (t >= off) ? sh[t - off] : 0;
    __syncthreads();
    sh[t] += u;
    __syncthreads();
  }
  if (i < N_NODES) offs[i] = sh[t] - v;  // local exclusive
  if (t == 255) bsum[blockIdx.x] = sh[255];
}

__global__ __launch_bounds__(256) void scan2(int* __restrict__ bsum) {
  __shared__ int sh[256];
  int t = threadIdx.x;
  int v = (t < SCAN_NBLK) ? bsum[t] : 0;
  sh[t] = v;
  __syncthreads();
#pragma unroll
  for (int off = 1; off < 256; off <<= 1) {
    int u = (t >= off) ? sh[t - off] : 0;
    __syncthreads();
    sh[t] += u;
    __syncthreads();
  }
  if (t < SCAN_NBLK) bsum[t] = sh[t] - v;  // exclusive block offsets
}

__global__ __launch_bounds__(256) void scan3(const int* __restrict__ bsum,
                                             int* __restrict__ offs,
                                             int* __restrict__ cursor) {
  int i = blockIdx.x * 256 + threadIdx.x;
  if (i < N_NODES) {
    int o = offs[i] + bsum[blockIdx.x];
    offs[i] = o;
    cursor[i] = o;
  }
  if (i == 0) offs[N_NODES] = N_EDGES;
}

// ---------------------------------------------------------------------------
// Scatter edges into dst-sorted lists: elsrc[pos]=src, elea[pos]=(a0,a1)
// ---------------------------------------------------------------------------
__global__ __launch_bounds__(256) void scatter_kernel(
    const int* __restrict__ ei, const float* __restrict__ ea,
    int* __restrict__ cursor, int* __restrict__ elsrc,
    float2* __restrict__ elea) {
  int e = blockIdx.x * 256 + threadIdx.x;
  if (e >= N_EDGES) return;
  int d = ei[N_EDGES + e];
  int pos = atomicAdd(&cursor[d], 1);
  elsrc[pos] = ei[e];
  elea[pos] = make_float2(ea[2 * e], ea[2 * e + 1]);
}

// ---------------------------------------------------------------------------
// W convert+transpose: Wt[n][k] = bf16(W[k][n]).  grid=128 (k), block=128 (n)
// ---------------------------------------------------------------------------
__global__ __launch_bounds__(128) void wconv(const float* __restrict__ W,
                                             u16* __restrict__ Wt) {
  int k = blockIdx.x;
  int n = threadIdx.x;
  Wt[n * HID + k] = f2bf(W[k * HID + n]);
}

// ---------------------------------------------------------------------------
// Aggregation d=128, bf16 in/out: out[i,:]=x[i,:]+sum_j relu(x[src_j]+ea@We+be)
// One wave per node; lane owns 2 features. No atomics.
// ---------------------------------------------------------------------------
__global__ __launch_bounds__(64) void aggregate128_bf16(
    const u16* __restrict__ xb, const int* __restrict__ offs,
    const int* __restrict__ elsrc, const float2* __restrict__ elea,
    const float* __restrict__ We, const float* __restrict__ be,
    u16* __restrict__ out) {
  int i = blockIdx.x;
  int c = threadIdx.x * 2;
  float2 we0 = *(const float2*)(We + c);
  float2 we1 = *(const float2*)(We + HID + c);
  float2 bec = *(const float2*)(be + c);
  ushort2 xs = *(const ushort2*)(xb + (size_t)i * HID + c);
  float acc0 = bf2f(xs.x), acc1 = bf2f(xs.y);
  int s0 = offs[i], s1 = offs[i + 1];
  for (int j = s0; j < s1; j++) {
    int s = elsrc[j];
    float2 a = elea[j];
    ushort2 u = *(const ushort2*)(xb + (size_t)s * HID + c);
    acc0 += fmaxf(bf2f(u.x) + a.x * we0.x + a.y * we1.x + bec.x, 0.f);
    acc1 += fmaxf(bf2f(u.y) + a.x * we0.y + a.y * we1.y + bec.y, 0.f);
  }
  ushort2 o;
  o.x = f2bf(acc0);
  o.y = f2bf(acc1);
  *(ushort2*)(out + (size_t)i * HID + c) = o;
}

// ---------------------------------------------------------------------------
// Aggregation d=16 (layer 0, f32 input x): 8 nodes per 128-thread block.
// ---------------------------------------------------------------------------
__global__ __launch_bounds__(128) void aggregate16(
    const float* __restrict__ x, const int* __restrict__ offs,
    const int* __restrict__ elsrc, const float2* __restrict__ elea,
    const float* __restrict__ We, const float* __restrict__ be,
    float* __restrict__ out) {
  int tid = threadIdx.x;
  int i = blockIdx.x * 8 + (tid >> 4);
  int c = tid & 15;
  float we0 = We[c], we1 = We[F_IN + c], bec = be[c];
  float acc = x[i * F_IN + c];
  int s0 = offs[i], s1 = offs[i + 1];
  for (int j = s0; j < s1; j++) {
    int s = elsrc[j];
    float2 a = elea[j];
    acc += fmaxf(x[s * F_IN + c] + a.x * we0 + a.y * we1 + bec, 0.f);
  }
  out[i * F_IN + c] = acc;
}

// ---------------------------------------------------------------------------
// MFMA bf16 GEMM: out[N,128] = A[N,128] @ W[128,128] + bias    (out bf16)
//   Wt is [n][k] bf16 (pre-transposed).  One wave per 16-row tile (grid-
//   strided); full B panel (8 col-tiles x 4 K-steps) resident in VGPRs.
//   PRO  : A element -> relu(a*scale[k]+shift[k]) before MFMA (BN+ReLU)
//   STATS: per-column sum/sumsq of (acc+bias) accumulated -> stat[256]
//   RELU : relu on output
// A-frag layout (16x16x32): A[m=lane&15][k=quad*8+j]; B[n=lane&15][k=...];
// C/D: col=lane&15, row=quad*4+reg.   [per cdna_hip_programming.md §3]
// ---------------------------------------------------------------------------
template <bool PRO, bool STATS, bool RELU>
__global__ __launch_bounds__(256, 2) void gemm_mfma(
    const u16* __restrict__ Ab, const u16* __restrict__ Wt,
    const float* __restrict__ bias, const float* __restrict__ scale,
    const float* __restrict__ shift, u16* __restrict__ outb,
    float* __restrict__ stat) {
  int tid = threadIdx.x;
  int lane = tid & 63;
  int wid = tid >> 6;
  int l15 = lane & 15;
  int quad = lane >> 4;
  int gwave = blockIdx.x * 4 + wid;
  int nwaves = gridDim.x * 4;

  // B fragments (resident): bfr[ct][ks] = Wt[ct*16+l15][ks*32+quad*8 .. +7]
  bf16x8 bfr[8][4];
#pragma unroll
  for (int ct = 0; ct < 8; ct++)
#pragma unroll
    for (int ks = 0; ks < 4; ks++)
      bfr[ct][ks] = __builtin_bit_cast(
          bf16x8, *(const u16x8*)(Wt + (size_t)(ct * 16 + l15) * HID +
                                  ks * 32 + quad * 8));

  float bv[8];
#pragma unroll
  for (int ct = 0; ct < 8; ct++) bv[ct] = bias[ct * 16 + l15];

  float s[8], q[8];
  if (STATS) {
#pragma unroll
    for (int ct = 0; ct < 8; ct++) {
      s[ct] = 0.f;
      q[ct] = 0.f;
    }
  }

  for (int t = gwave; t < NT_ROWS; t += nwaves) {
    int r0 = t * 16;
    const u16* arow = Ab + (size_t)(r0 + l15) * HID + quad * 8;
    bf16x8 af[4];
#pragma unroll
    for (int ks = 0; ks < 4; ks++) {
      u16x8 raw = *(const u16x8*)(arow + ks * 32);
      if (PRO) {
        u16x8 pr;
#pragma unroll
        for (int j = 0; j < 8; j++) {
          int k = ks * 32 + quad * 8 + j;
          float v = bf2f(raw[j]);
          v = fmaxf(v * scale[k] + shift[k], 0.f);
          pr[j] = f2bf(v);
        }
        raw = pr;
      }
      af[ks] = __builtin_bit_cast(bf16x8, raw);
    }

    f32x4 acc[8];
#pragma unroll
    for (int ct = 0; ct < 8; ct++) acc[ct] = (f32x4){0.f, 0.f, 0.f, 0.f};
#pragma unroll
    for (int ks = 0; ks < 4; ks++)
#pragma unroll
      for (int ct = 0; ct < 8; ct++)
        acc[ct] = __builtin_amdgcn_mfma_f32_16x16x32_bf16(af[ks], bfr[ct][ks],
                                                          acc[ct], 0, 0, 0);

#pragma unroll
    for (int ct = 0; ct < 8; ct++) {
      u16* op = outb + (size_t)(r0 + quad * 4) * HID + ct * 16 + l15;
#pragma unroll
      for (int r = 0; r < 4; r++) {
        float h = acc[ct][r] + bv[ct];
        if (STATS) {
          s[ct] += h;
          q[ct] += h * h;
        }
        if (RELU) h = fmaxf(h, 0.f);
        op[(size_t)r * HID] = f2bf(h);
      }
    }
  }

  if (STATS) {
    __shared__ float sred[4][256];
#pragma unroll
    for (int ct = 0; ct < 8; ct++) {
      float sv = s[ct], qv = q[ct];
      sv += __shfl_xor(sv, 16);
      sv += __shfl_xor(sv, 32);
      qv += __shfl_xor(qv, 16);
      qv += __shfl_xor(qv, 32);
      if (quad == 0) {
        sred[wid][ct * 16 + l15] = sv;
        sred[wid][128 + ct * 16 + l15] = qv;
      }
    }
    __syncthreads();
    float tot = sred[0][tid] + sred[1][tid] + sred[2][tid] + sred[3][tid];
    atomicAdd(stat + tid, tot);
  }
}

// ---------------------------------------------------------------------------
// f32 GEMM for layer-0 K=16 (cheap): out bf16 + stats.
// ---------------------------------------------------------------------------
__global__ __launch_bounds__(256) void gemm16_f32(
    const float* __restrict__ A, const float* __restrict__ W,
    const float* __restrict__ bias, u16* __restrict__ outb,
    float* __restrict__ stat) {
  constexpr int KT = 16;
  __shared__ float Wl[KT][HID];
  __shared__ float Al[32][KT];
  __shared__ float red[8][2][HID];

  int tid = threadIdx.x;
  int cg = tid & 31;
  int rg = tid >> 5;
  int c = cg << 2;
  int row0 = blockIdx.x * 32;

  float4 acc[4];
#pragma unroll
  for (int i = 0; i < 4; i++) acc[i] = make_float4(0.f, 0.f, 0.f, 0.f);

  for (int i = tid; i < KT * (HID / 4); i += 256) {
    int k = i >> 5;
    int cc = (i & 31) << 2;
    *(float4*)&Wl[k][cc] = *(const float4*)(W + k * HID + cc);
  }
  for (int i = tid; i < 32 * KT / 4; i += 256) {
    int r = i / (KT / 4);
    int k4 = (i % (KT / 4)) << 2;
    *(float4*)&Al[r][k4] = *(const float4*)(A + (size_t)(row0 + r) * KT + k4);
  }
  __syncthreads();
#pragma unroll
  for (int k = 0; k < KT; k++) {
    float4 w4 = *(float4*)&Wl[k][c];
#pragma unroll
    for (int i = 0; i < 4; i++) {
      float a = Al[rg * 4 + i][k];
      acc[i].x += a * w4.x;
      acc[i].y += a * w4.y;
      acc[i].z += a * w4.z;
      acc[i].w += a * w4.w;
    }
  }

  float4 bv = *(const float4*)(bias + c);
  float4 sm = make_float4(0.f, 0.f, 0.f, 0.f);
  float4 qm = make_float4(0.f, 0.f, 0.f, 0.f);
#pragma unroll
  for (int i = 0; i < 4; i++) {
    acc[i].x += bv.x; acc[i].y += bv.y; acc[i].z += bv.z; acc[i].w += bv.w;
    sm.x += acc[i].x; sm.y += acc[i].y; sm.z += acc[i].z; sm.w += acc[i].w;
    qm.x += acc[i].x * acc[i].x; qm.y += acc[i].y * acc[i].y;
    qm.z += acc[i].z * acc[i].z; qm.w += acc[i].w * acc[i].w;
    ushort4 o16;
    o16.x = f2bf(acc[i].x); o16.y = f2bf(acc[i].y);
    o16.z = f2bf(acc[i].z); o16.w = f2bf(acc[i].w);
    *(ushort4*)(outb + (size_t)(row0 + rg * 4 + i) * HID + c) = o16;
  }
  *(float4*)&red[rg][0][c] = sm;
  *(float4*)&red[rg][1][c] = qm;
  __syncthreads();
  if (tid < HID) {
    float sv = 0.f, qv = 0.f;
#pragma unroll
    for (int r = 0; r < 8; r++) {
      sv += red[r][0][tid];
      qv += red[r][1][tid];
    }
    atomicAdd(stat + tid, sv);
    atomicAdd(stat + HID + tid, qv);
  }
}

// ---------------------------------------------------------------------------
__global__ void bn_finalize(const float* __restrict__ stat,
                            const float* __restrict__ g,
                            const float* __restrict__ bt,
                            float* __restrict__ ss) {
  int c = threadIdx.x;  // 128 threads
  float mu = stat[c] / (float)N_NODES;
  float var = stat[HID + c] / (float)N_NODES - mu * mu;
  float sc = g[c] * rsqrtf(var + BN_EPS);
  ss[c] = sc;
  ss[HID + c] = bt[c] - mu * sc;
}

// ---------------------------------------------------------------------------
// Batch pooling over bf16 x (batch sorted): flush on segment change.
// ---------------------------------------------------------------------------
__global__ __launch_bounds__(128) void pool_kernel(
    const u16* __restrict__ xb, const int* __restrict__ batch,
    float* __restrict__ pooled) {
  int c = threadIdx.x;
  int r0 = blockIdx.x * 160;
  int r1 = r0 + 160;
  if (r1 > N_NODES) r1 = N_NODES;
  float acc = 0.f;
  int cur = batch[r0];
  for (int r = r0; r < r1; r++) {
    int b = batch[r];
    if (b != cur) {
      atomicAdd(pooled + cur * HID + c, acc);
      acc = 0.f;
      cur = b;
    }
    acc += bf2f(xb[(size_t)r * HID + c]);
  }
  atomicAdd(pooled + cur * HID + c, acc);
}

// ---------------------------------------------------------------------------
__global__ __launch_bounds__(128) void final_mlp(
    const float* __restrict__ pooled, const float* __restrict__ Wf1,
    const float* __restrict__ bf1, const float* __restrict__ Wf2,
    const float* __restrict__ bf2, float* __restrict__ out) {
  __shared__ float pr[HID];
  __shared__ float h[HID];
  int b = blockIdx.x, c = threadIdx.x;
  pr[c] = pooled[b * HID + c];
  __syncthreads();
  float acc = bf1[c];
  for (int k = 0; k < HID; k++) acc += pr[k] * Wf1[k * HID + c];
  h[c] = fmaxf(acc, 0.f);
  __syncthreads();
  if (c < 8) {
    float o = bf2[c];
    for (int k = 0; k < HID; k++) o += h[k] * Wf2[k * 8 + c];
    out[b * 8 + c] = o;
  }
}

// ---------------------------------------------------------------------------
extern "C" void kernel_launch(void* const* d_in, const int* in_sizes, int n_in,
                              void* d_out, int out_size, void* d_ws,
                              size_t ws_size, hipStream_t stream) {
  const float* x_in = (const float*)d_in[0];
  const int* ei = (const int*)d_in[1];
  const float* ea = (const float*)d_in[2];
  const int* batch = (const int*)d_in[3];
  const float* We[3], *be[3], *W1[3], *b1[3], *g[3], *bt[3], *W2[3], *b2[3];
  for (int l = 0; l < 3; l++) {
    int i0 = 5 + 8 * l;
    We[l] = (const float*)d_in[i0 + 0];
    be[l] = (const float*)d_in[i0 + 1];
    W1[l] = (const float*)d_in[i0 + 2];
    b1[l] = (const float*)d_in[i0 + 3];
    g[l] = (const float*)d_in[i0 + 4];
    bt[l] = (const float*)d_in[i0 + 5];
    W2[l] = (const float*)d_in[i0 + 6];
    b2[l] = (const float*)d_in[i0 + 7];
  }
  const float* Wf1 = (const float*)d_in[29];
  const float* bf1 = (const float*)d_in[30];
  const float* Wf2 = (const float*)d_in[31];
  const float* bf2 = (const float*)d_in[32];
  float* out = (float*)d_out;

  const size_t NH = (size_t)N_NODES * HID;
  // workspace layout (all counts even -> 8B alignment preserved)
  u16* xb = (u16*)d_ws;                  // [N,128] bf16 layer output
  u16* abuf = xb + NH;                   // [N,128] bf16 aggregation
  u16* hbuf = abuf + NH;                 // [N,128] bf16 hidden (pre-BN)
  float* agg16 = (float*)(hbuf + NH);    // [N,16] f32
  float* stat = agg16 + (size_t)N_NODES * F_IN;  // [256]
  float* ss = stat + 256;                // [256]
  float* pooled = ss + 256;              // [64,128]
  u16* wt[5];                            // 5 x [128,128] bf16 transposed
  wt[0] = (u16*)(pooled + NB * HID);
  for (int i = 1; i < 5; i++) wt[i] = wt[i - 1] + HID * HID;
  int* deg = (int*)(wt[4] + HID * HID);  // [40000]
  int* offs = deg + N_NODES;             // [40001 pad 1]
  int* cursor = offs + N_NODES + 2;      // [40000]
  int* bsum = cursor + N_NODES;          // [256]
  float2* elea = (float2*)(bsum + 256);  // [E]
  int* elsrc = (int*)(elea + N_EDGES);   // [E]
  // wt order: [0]=W2t l0, [1]=W1t l1, [2]=W2t l1, [3]=W1t l2, [4]=W2t l2

  // ---------------- CSR build (dst-sorted edge list) ----------------
  hipMemsetAsync(deg, 0, N_NODES * sizeof(int), stream);
  hipLaunchKernelGGL(hist_kernel, dim3((N_EDGES + 255) / 256), dim3(256), 0,
                     stream, ei, deg);
  hipLaunchKernelGGL(scan1, dim3(SCAN_NBLK), dim3(256), 0, stream, deg, offs,
                     bsum);
  hipLaunchKernelGGL(scan2, dim3(1), dim3(256), 0, stream, bsum);
  hipLaunchKernelGGL(scan3, dim3(SCAN_NBLK), dim3(256), 0, stream, bsum, offs,
                     cursor);
  hipLaunchKernelGGL(scatter_kernel, dim3((N_EDGES + 255) / 256), dim3(256), 0,
                     stream, ei, ea, cursor, elsrc, elea);

  // ---------------- W transposes (bf16) ----------------
  hipLaunchKernelGGL(wconv, dim3(HID), dim3(HID), 0, stream, W2[0], wt[0]);
  hipLaunchKernelGGL(wconv, dim3(HID), dim3(HID), 0, stream, W1[1], wt[1]);
  hipLaunchKernelGGL(wconv, dim3(HID), dim3(HID), 0, stream, W2[1], wt[2]);
  hipLaunchKernelGGL(wconv, dim3(HID), dim3(HID), 0, stream, W1[2], wt[3]);
  hipLaunchKernelGGL(wconv, dim3(HID), dim3(HID), 0, stream, W2[2], wt[4]);

  const int GMB = 313;  // gemm_mfma grid: 1252 waves, 2 tiles/wave

  // ---------------- Layer 0 (d = 16) ----------------
  hipLaunchKernelGGL(aggregate16, dim3(N_NODES / 8), dim3(128), 0, stream,
                     x_in, offs, elsrc, elea, We[0], be[0], agg16);
  hipMemsetAsync(stat, 0, 256 * sizeof(float), stream);
  hipLaunchKernelGGL(gemm16_f32, dim3(N_NODES / 32), dim3(256), 0, stream,
                     agg16, W1[0], b1[0], hbuf, stat);
  hipLaunchKernelGGL(bn_finalize, dim3(1), dim3(128), 0, stream, stat, g[0],
                     bt[0], ss);
  hipLaunchKernelGGL((gemm_mfma<true, false, true>), dim3(GMB), dim3(256), 0,
                     stream, hbuf, wt[0], b2[0], ss, ss + HID, xb, nullptr);

  // ---------------- Layers 1, 2 (d = 128) ----------------
  for (int l = 1; l < 3; l++) {
    hipLaunchKernelGGL(aggregate128_bf16, dim3(N_NODES), dim3(64), 0, stream,
                       xb, offs, elsrc, elea, We[l], be[l], abuf);
    hipMemsetAsync(stat, 0, 256 * sizeof(float), stream);
    hipLaunchKernelGGL((gemm_mfma<false, true, false>), dim3(GMB), dim3(256),
                       0, stream, abuf, wt[2 * l - 1], b1[l], nullptr, nullptr,
                       hbuf, stat);
    hipLaunchKernelGGL(bn_finalize, dim3(1), dim3(128), 0, stream, stat, g[l],
                       bt[l], ss);
    hipLaunchKernelGGL((gemm_mfma<true, false, true>), dim3(GMB), dim3(256), 0,
                       stream, hbuf, wt[2 * l], b2[l], ss, ss + HID, xb,
                       nullptr);
  }

  // ---------------- Pool + final MLP ----------------
  hipMemsetAsync(pooled, 0, (size_t)NB * HID * sizeof(float), stream);
  hipLaunchKernelGGL(pool_kernel, dim3(N_NODES / 160), dim3(128), 0, stream,
                     xb, batch, pooled);
  hipLaunchKernelGGL(final_mlp, dim3(NB), dim3(128), 0, stream, pooled, Wf1,
                     bf1, Wf2, bf2, out);
}

// Round 6
// 473.197 us; speedup vs baseline: 5.6525x; 1.0728x over previous
//
#include <hip/hip_runtime.h>
#include <hip/hip_bf16.h>

#define N_NODES 40000
#define N_EDGES 640000
#define HID 128
#define NB 64
#define F_IN 16
#define BN_EPS 1e-5f
#define SCAN_NBLK ((N_NODES + 255) / 256)  // 157
#define NT_ROWS (N_NODES / 16)             // 2500 row-tiles
#define POOL_ROWS 40
#define POOL_NBLK (N_NODES / POOL_ROWS)    // 1000

typedef unsigned short u16;
typedef unsigned int u32;
typedef __attribute__((ext_vector_type(8))) __bf16 bf16x8;
typedef __attribute__((ext_vector_type(8))) unsigned short u16x8;
typedef __attribute__((ext_vector_type(4))) float f32x4;

__device__ __forceinline__ float bf2f(u16 u) {
  u32 v = ((u32)u) << 16;
  return __builtin_bit_cast(float, v);
}
__device__ __forceinline__ u16 f2bf(float f) {
  u32 v = __builtin_bit_cast(u32, f);
  u32 r = 0x7FFFu + ((v >> 16) & 1u);  // round-to-nearest-even
  return (u16)((v + r) >> 16);
}

// ---------------------------------------------------------------------------
// CSR build: histogram of dst degrees
// ---------------------------------------------------------------------------
__global__ __launch_bounds__(256) void hist_kernel(const int* __restrict__ ei,
                                                   int* __restrict__ deg) {
  int e = blockIdx.x * 256 + threadIdx.x;
  if (e < N_EDGES) atomicAdd(&deg[ei[N_EDGES + e]], 1);
}

// ---------------------------------------------------------------------------
// 3-phase hierarchical exclusive scan of deg[N] -> offs, cursor
// ---------------------------------------------------------------------------
__global__ __launch_bounds__(256) void scan1(const int* __restrict__ deg,
                                             int* __restrict__ offs,
                                             int* __restrict__ bsum) {
  __shared__ int sh[256];
  int t = threadIdx.x;
  int i = blockIdx.x * 256 + t;
  int v = (i < N_NODES) ? deg[i] : 0;
  sh[t] = v;
  __syncthreads();
#pragma unroll
  for (int off = 1; off < 256; off <<= 1) {
    int u = (t >= off) ? sh[t - off] : 0;
    __syncthreads();
    sh[t] += u;
    __syncthreads();
  }
  if (i < N_NODES) offs[i] = sh[t] - v;  // local exclusive
  if (t == 255) bsum[blockIdx.x] = sh[255];
}

__global__ __launch_bounds__(256) void scan2(int* __restrict__ bsum) {
  __shared__ int sh[256];
  int t = threadIdx.x;
  int v = (t < SCAN_NBLK) ? bsum[t] : 0;
  sh[t] = v;
  __syncthreads();
#pragma unroll
  for (int off = 1; off < 256; off <<= 1) {
    int u = (t >= off) ? sh[t - off] : 0;
    __syncthreads();
    sh[t] += u;
    __syncthreads();
  }
  if (t < SCAN_NBLK) bsum[t] = sh[t] - v;  // exclusive block offsets
}

__global__ __launch_bounds__(256) void scan3(const int* __restrict__ bsum,
                                             int* __restrict__ offs,
                                             int* __restrict__ cursor) {
  int i = blockIdx.x * 256 + threadIdx.x;
  if (i < N_NODES) {
    int o = offs[i] + bsum[blockIdx.x];
    offs[i] = o;
    cursor[i] = o;
  }
  if (i == 0) offs[N_NODES] = N_EDGES;
}

// ---------------------------------------------------------------------------
// Scatter edges into dst-sorted lists: elsrc[pos]=src, elea[pos]=(a0,a1)
// ---------------------------------------------------------------------------
__global__ __launch_bounds__(256) void scatter_kernel(
    const int* __restrict__ ei, const float* __restrict__ ea,
    int* __restrict__ cursor, int* __restrict__ elsrc,
    float2* __restrict__ elea) {
  int e = blockIdx.x * 256 + threadIdx.x;
  if (e >= N_EDGES) return;
  int d = ei[N_EDGES + e];
  int pos = atomicAdd(&cursor[d], 1);
  elsrc[pos] = ei[e];
  elea[pos] = make_float2(ea[2 * e], ea[2 * e + 1]);
}

// ---------------------------------------------------------------------------
// W convert+transpose: Wt[n][k] = bf16(W[k][n]).  grid=128 (k), block=128 (n)
// ---------------------------------------------------------------------------
__global__ __launch_bounds__(128) void wconv(const float* __restrict__ W,
                                             u16* __restrict__ Wt) {
  int k = blockIdx.x;
  int n = threadIdx.x;
  Wt[n * HID + k] = f2bf(W[k * HID + n]);
}

// ---------------------------------------------------------------------------
// Aggregation d=128, bf16 in/out: out[i,:]=x[i,:]+sum_j relu(x[src_j]+ea@We+be)
// One wave per node; lane owns 2 features. No atomics.
// ---------------------------------------------------------------------------
__global__ __launch_bounds__(64) void aggregate128_bf16(
    const u16* __restrict__ xb, const int* __restrict__ offs,
    const int* __restrict__ elsrc, const float2* __restrict__ elea,
    const float* __restrict__ We, const float* __restrict__ be,
    u16* __restrict__ out) {
  int i = blockIdx.x;
  int c = threadIdx.x * 2;
  float2 we0 = *(const float2*)(We + c);
  float2 we1 = *(const float2*)(We + HID + c);
  float2 bec = *(const float2*)(be + c);
  ushort2 xs = *(const ushort2*)(xb + (size_t)i * HID + c);
  float acc0 = bf2f(xs.x), acc1 = bf2f(xs.y);
  int s0 = offs[i], s1 = offs[i + 1];
  for (int j = s0; j < s1; j++) {
    int s = elsrc[j];
    float2 a = elea[j];
    ushort2 u = *(const ushort2*)(xb + (size_t)s * HID + c);
    acc0 += fmaxf(bf2f(u.x) + a.x * we0.x + a.y * we1.x + bec.x, 0.f);
    acc1 += fmaxf(bf2f(u.y) + a.x * we0.y + a.y * we1.y + bec.y, 0.f);
  }
  ushort2 o;
  o.x = f2bf(acc0);
  o.y = f2bf(acc1);
  *(ushort2*)(out + (size_t)i * HID + c) = o;
}

// ---------------------------------------------------------------------------
// Aggregation d=16 (layer 0, f32 input x): 8 nodes per 128-thread block.
// ---------------------------------------------------------------------------
__global__ __launch_bounds__(128) void aggregate16(
    const float* __restrict__ x, const int* __restrict__ offs,
    const int* __restrict__ elsrc, const float2* __restrict__ elea,
    const float* __restrict__ We, const float* __restrict__ be,
    float* __restrict__ out) {
  int tid = threadIdx.x;
  int i = blockIdx.x * 8 + (tid >> 4);
  int c = tid & 15;
  float we0 = We[c], we1 = We[F_IN + c], bec = be[c];
  float acc = x[i * F_IN + c];
  int s0 = offs[i], s1 = offs[i + 1];
  for (int j = s0; j < s1; j++) {
    int s = elsrc[j];
    float2 a = elea[j];
    acc += fmaxf(x[s * F_IN + c] + a.x * we0 + a.y * we1 + bec, 0.f);
  }
  out[i * F_IN + c] = acc;
}

// ---------------------------------------------------------------------------
// MFMA bf16 GEMM: out[N,128] = A[N,128] @ W[128,128] + bias    (out bf16)
//   Wt is [n][k] bf16 (pre-transposed).  One wave per 16-row tile (grid-
//   strided); full B panel (8 col-tiles x 4 K-steps) resident in VGPRs.
//   PRO  : A element -> relu(a*scale[k]+shift[k]) before MFMA (BN+ReLU)
//   STATS: per-column sum/sumsq of (acc+bias) accumulated -> stat[256]
//   RELU : relu on output
// ---------------------------------------------------------------------------
template <bool PRO, bool STATS, bool RELU>
__global__ __launch_bounds__(256, 2) void gemm_mfma(
    const u16* __restrict__ Ab, const u16* __restrict__ Wt,
    const float* __restrict__ bias, const float* __restrict__ scale,
    const float* __restrict__ shift, u16* __restrict__ outb,
    float* __restrict__ stat) {
  int tid = threadIdx.x;
  int lane = tid & 63;
  int wid = tid >> 6;
  int l15 = lane & 15;
  int quad = lane >> 4;
  int gwave = blockIdx.x * 4 + wid;
  int nwaves = gridDim.x * 4;

  bf16x8 bfr[8][4];
#pragma unroll
  for (int ct = 0; ct < 8; ct++)
#pragma unroll
    for (int ks = 0; ks < 4; ks++)
      bfr[ct][ks] = __builtin_bit_cast(
          bf16x8, *(const u16x8*)(Wt + (size_t)(ct * 16 + l15) * HID +
                                  ks * 32 + quad * 8));

  float bv[8];
#pragma unroll
  for (int ct = 0; ct < 8; ct++) bv[ct] = bias[ct * 16 + l15];

  float s[8], q[8];
  if (STATS) {
#pragma unroll
    for (int ct = 0; ct < 8; ct++) {
      s[ct] = 0.f;
      q[ct] = 0.f;
    }
  }

  for (int t = gwave; t < NT_ROWS; t += nwaves) {
    int r0 = t * 16;
    const u16* arow = Ab + (size_t)(r0 + l15) * HID + quad * 8;
    bf16x8 af[4];
#pragma unroll
    for (int ks = 0; ks < 4; ks++) {
      u16x8 raw = *(const u16x8*)(arow + ks * 32);
      if (PRO) {
        u16x8 pr;
#pragma unroll
        for (int j = 0; j < 8; j++) {
          int k = ks * 32 + quad * 8 + j;
          float v = bf2f(raw[j]);
          v = fmaxf(v * scale[k] + shift[k], 0.f);
          pr[j] = f2bf(v);
        }
        raw = pr;
      }
      af[ks] = __builtin_bit_cast(bf16x8, raw);
    }

    f32x4 acc[8];
#pragma unroll
    for (int ct = 0; ct < 8; ct++) acc[ct] = (f32x4){0.f, 0.f, 0.f, 0.f};
#pragma unroll
    for (int ks = 0; ks < 4; ks++)
#pragma unroll
      for (int ct = 0; ct < 8; ct++)
        acc[ct] = __builtin_amdgcn_mfma_f32_16x16x32_bf16(af[ks], bfr[ct][ks],
                                                          acc[ct], 0, 0, 0);

#pragma unroll
    for (int ct = 0; ct < 8; ct++) {
      u16* op = outb + (size_t)(r0 + quad * 4) * HID + ct * 16 + l15;
#pragma unroll
      for (int r = 0; r < 4; r++) {
        float h = acc[ct][r] + bv[ct];
        if (STATS) {
          s[ct] += h;
          q[ct] += h * h;
        }
        if (RELU) h = fmaxf(h, 0.f);
        op[(size_t)r * HID] = f2bf(h);
      }
    }
  }

  if (STATS) {
    __shared__ float sred[4][256];
#pragma unroll
    for (int ct = 0; ct < 8; ct++) {
      float sv = s[ct], qv = q[ct];
      sv += __shfl_xor(sv, 16);
      sv += __shfl_xor(sv, 32);
      qv += __shfl_xor(qv, 16);
      qv += __shfl_xor(qv, 32);
      if (quad == 0) {
        sred[wid][ct * 16 + l15] = sv;
        sred[wid][128 + ct * 16 + l15] = qv;
      }
    }
    __syncthreads();
    float tot = sred[0][tid] + sred[1][tid] + sred[2][tid] + sred[3][tid];
    atomicAdd(stat + tid, tot);
  }
}

// ---------------------------------------------------------------------------
// f32 GEMM for layer-0 K=16 (cheap): out bf16 + stats.
// ---------------------------------------------------------------------------
__global__ __launch_bounds__(256) void gemm16_f32(
    const float* __restrict__ A, const float* __restrict__ W,
    const float* __restrict__ bias, u16* __restrict__ outb,
    float* __restrict__ stat) {
  constexpr int KT = 16;
  __shared__ float Wl[KT][HID];
  __shared__ float Al[32][KT];
  __shared__ float red[8][2][HID];

  int tid = threadIdx.x;
  int cg = tid & 31;
  int rg = tid >> 5;
  int c = cg << 2;
  int row0 = blockIdx.x * 32;

  float4 acc[4];
#pragma unroll
  for (int i = 0; i < 4; i++) acc[i] = make_float4(0.f, 0.f, 0.f, 0.f);

  for (int i = tid; i < KT * (HID / 4); i += 256) {
    int k = i >> 5;
    int cc = (i & 31) << 2;
    *(float4*)&Wl[k][cc] = *(const float4*)(W + k * HID + cc);
  }
  for (int i = tid; i < 32 * KT / 4; i += 256) {
    int r = i / (KT / 4);
    int k4 = (i % (KT / 4)) << 2;
    *(float4*)&Al[r][k4] = *(const float4*)(A + (size_t)(row0 + r) * KT + k4);
  }
  __syncthreads();
#pragma unroll
  for (int k = 0; k < KT; k++) {
    float4 w4 = *(float4*)&Wl[k][c];
#pragma unroll
    for (int i = 0; i < 4; i++) {
      float a = Al[rg * 4 + i][k];
      acc[i].x += a * w4.x;
      acc[i].y += a * w4.y;
      acc[i].z += a * w4.z;
      acc[i].w += a * w4.w;
    }
  }

  float4 bv = *(const float4*)(bias + c);
  float4 sm = make_float4(0.f, 0.f, 0.f, 0.f);
  float4 qm = make_float4(0.f, 0.f, 0.f, 0.f);
#pragma unroll
  for (int i = 0; i < 4; i++) {
    acc[i].x += bv.x; acc[i].y += bv.y; acc[i].z += bv.z; acc[i].w += bv.w;
    sm.x += acc[i].x; sm.y += acc[i].y; sm.z += acc[i].z; sm.w += acc[i].w;
    qm.x += acc[i].x * acc[i].x; qm.y += acc[i].y * acc[i].y;
    qm.z += acc[i].z * acc[i].z; qm.w += acc[i].w * acc[i].w;
    ushort4 o16;
    o16.x = f2bf(acc[i].x); o16.y = f2bf(acc[i].y);
    o16.z = f2bf(acc[i].z); o16.w = f2bf(acc[i].w);
    *(ushort4*)(outb + (size_t)(row0 + rg * 4 + i) * HID + c) = o16;
  }
  *(float4*)&red[rg][0][c] = sm;
  *(float4*)&red[rg][1][c] = qm;
  __syncthreads();
  if (tid < HID) {
    float sv = 0.f, qv = 0.f;
#pragma unroll
    for (int r = 0; r < 8; r++) {
      sv += red[r][0][tid];
      qv += red[r][1][tid];
    }
    atomicAdd(stat + tid, sv);
    atomicAdd(stat + HID + tid, qv);
  }
}

// ---------------------------------------------------------------------------
__global__ void bn_finalize(const float* __restrict__ stat,
                            const float* __restrict__ g,
                            const float* __restrict__ bt,
                            float* __restrict__ ss) {
  int c = threadIdx.x;  // 128 threads
  float mu = stat[c] / (float)N_NODES;
  float var = stat[HID + c] / (float)N_NODES - mu * mu;
  float sc = g[c] * rsqrtf(var + BN_EPS);
  ss[c] = sc;
  ss[HID + c] = bt[c] - mu * sc;
}

// ---------------------------------------------------------------------------
// Batch pooling over bf16 x (batch sorted): 1000 blocks x 1 wave, 40 rows
// each, lane owns 2 features (ushort2). Flush on segment change only.
// ---------------------------------------------------------------------------
__global__ __launch_bounds__(64) void pool_kernel(
    const u16* __restrict__ xb, const int* __restrict__ batch,
    float* __restrict__ pooled) {
  int c = threadIdx.x * 2;
  int r0 = blockIdx.x * POOL_ROWS;
  int r1 = r0 + POOL_ROWS;
  if (r1 > N_NODES) r1 = N_NODES;
  float a0 = 0.f, a1 = 0.f;
  int cur = batch[r0];
  for (int r = r0; r < r1; r++) {
    int b = batch[r];
    if (b != cur) {
      atomicAdd(pooled + cur * HID + c, a0);
      atomicAdd(pooled + cur * HID + c + 1, a1);
      a0 = 0.f;
      a1 = 0.f;
      cur = b;
    }
    ushort2 u = *(const ushort2*)(xb + (size_t)r * HID + c);
    a0 += bf2f(u.x);
    a1 += bf2f(u.y);
  }
  atomicAdd(pooled + cur * HID + c, a0);
  atomicAdd(pooled + cur * HID + c + 1, a1);
}

// ---------------------------------------------------------------------------
__global__ __launch_bounds__(128) void final_mlp(
    const float* __restrict__ pooled, const float* __restrict__ Wf1,
    const float* __restrict__ bf1, const float* __restrict__ Wf2,
    const float* __restrict__ bf2, float* __restrict__ out) {
  __shared__ float pr[HID];
  __shared__ float h[HID];
  int b = blockIdx.x, c = threadIdx.x;
  pr[c] = pooled[b * HID + c];
  __syncthreads();
  float acc = bf1[c];
  for (int k = 0; k < HID; k++) acc += pr[k] * Wf1[k * HID + c];
  h[c] = fmaxf(acc, 0.f);
  __syncthreads();
  if (c < 8) {
    float o = bf2[c];
    for (int k = 0; k < HID; k++) o += h[k] * Wf2[k * 8 + c];
    out[b * 8 + c] = o;
  }
}

// ---------------------------------------------------------------------------
extern "C" void kernel_launch(void* const* d_in, const int* in_sizes, int n_in,
                              void* d_out, int out_size, void* d_ws,
                              size_t ws_size, hipStream_t stream) {
  const float* x_in = (const float*)d_in[0];
  const int* ei = (const int*)d_in[1];
  const float* ea = (const float*)d_in[2];
  const int* batch = (const int*)d_in[3];
  const float* We[3], *be[3], *W1[3], *b1[3], *g[3], *bt[3], *W2[3], *b2[3];
  for (int l = 0; l < 3; l++) {
    int i0 = 5 + 8 * l;
    We[l] = (const float*)d_in[i0 + 0];
    be[l] = (const float*)d_in[i0 + 1];
    W1[l] = (const float*)d_in[i0 + 2];
    b1[l] = (const float*)d_in[i0 + 3];
    g[l] = (const float*)d_in[i0 + 4];
    bt[l] = (const float*)d_in[i0 + 5];
    W2[l] = (const float*)d_in[i0 + 6];
    b2[l] = (const float*)d_in[i0 + 7];
  }
  const float* Wf1 = (const float*)d_in[29];
  const float* bf1 = (const float*)d_in[30];
  const float* Wf2 = (const float*)d_in[31];
  const float* bf2 = (const float*)d_in[32];
  float* out = (float*)d_out;

  const size_t NH = (size_t)N_NODES * HID;
  u16* xb = (u16*)d_ws;                  // [N,128] bf16 layer output
  u16* abuf = xb + NH;                   // [N,128] bf16 aggregation
  u16* hbuf = abuf + NH;                 // [N,128] bf16 hidden (pre-BN)
  float* agg16 = (float*)(hbuf + NH);    // [N,16] f32
  float* stat = agg16 + (size_t)N_NODES * F_IN;  // [256]
  float* ss = stat + 256;                // [256]
  float* pooled = ss + 256;              // [64,128]
  u16* wt[5];                            // 5 x [128,128] bf16 transposed
  wt[0] = (u16*)(pooled + NB * HID);
  for (int i = 1; i < 5; i++) wt[i] = wt[i - 1] + HID * HID;
  int* deg = (int*)(wt[4] + HID * HID);  // [40000]
  int* offs = deg + N_NODES;             // [40001 pad 1]
  int* cursor = offs + N_NODES + 2;      // [40000]
  int* bsum = cursor + N_NODES;          // [256]
  float2* elea = (float2*)(bsum + 256);  // [E]
  int* elsrc = (int*)(elea + N_EDGES);   // [E]
  // wt order: [0]=W2t l0, [1]=W1t l1, [2]=W2t l1, [3]=W1t l2, [4]=W2t l2

  // ---------------- CSR build (dst-sorted edge list) ----------------
  hipMemsetAsync(deg, 0, N_NODES * sizeof(int), stream);
  hipLaunchKernelGGL(hist_kernel, dim3((N_EDGES + 255) / 256), dim3(256), 0,
                     stream, ei, deg);
  hipLaunchKernelGGL(scan1, dim3(SCAN_NBLK), dim3(256), 0, stream, deg, offs,
                     bsum);
  hipLaunchKernelGGL(scan2, dim3(1), dim3(256), 0, stream, bsum);
  hipLaunchKernelGGL(scan3, dim3(SCAN_NBLK), dim3(256), 0, stream, bsum, offs,
                     cursor);
  hipLaunchKernelGGL(scatter_kernel, dim3((N_EDGES + 255) / 256), dim3(256), 0,
                     stream, ei, ea, cursor, elsrc, elea);

  // ---------------- W transposes (bf16) ----------------
  hipLaunchKernelGGL(wconv, dim3(HID), dim3(HID), 0, stream, W2[0], wt[0]);
  hipLaunchKernelGGL(wconv, dim3(HID), dim3(HID), 0, stream, W1[1], wt[1]);
  hipLaunchKernelGGL(wconv, dim3(HID), dim3(HID), 0, stream, W2[1], wt[2]);
  hipLaunchKernelGGL(wconv, dim3(HID), dim3(HID), 0, stream, W1[2], wt[3]);
  hipLaunchKernelGGL(wconv, dim3(HID), dim3(HID), 0, stream, W2[2], wt[4]);

  const int GMB = 313;  // gemm_mfma grid: 1252 waves, 2 tiles/wave

  // ---------------- Layer 0 (d = 16) ----------------
  hipLaunchKernelGGL(aggregate16, dim3(N_NODES / 8), dim3(128), 0, stream,
                     x_in, offs, elsrc, elea, We[0], be[0], agg16);
  hipMemsetAsync(stat, 0, 256 * sizeof(float), stream);
  hipLaunchKernelGGL(gemm16_f32, dim3(N_NODES / 32), dim3(256), 0, stream,
                     agg16, W1[0], b1[0], hbuf, stat);
  hipLaunchKernelGGL(bn_finalize, dim3(1), dim3(128), 0, stream, stat, g[0],
                     bt[0], ss);
  hipLaunchKernelGGL((gemm_mfma<true, false, true>), dim3(GMB), dim3(256), 0,
                     stream, hbuf, wt[0], b2[0], ss, ss + HID, xb, nullptr);

  // ---------------- Layers 1, 2 (d = 128) ----------------
  for (int l = 1; l < 3; l++) {
    hipLaunchKernelGGL(aggregate128_bf16, dim3(N_NODES), dim3(64), 0, stream,
                       xb, offs, elsrc, elea, We[l], be[l], abuf);
    hipMemsetAsync(stat, 0, 256 * sizeof(float), stream);
    hipLaunchKernelGGL((gemm_mfma<false, true, false>), dim3(GMB), dim3(256),
                       0, stream, abuf, wt[2 * l - 1], b1[l], nullptr, nullptr,
                       hbuf, stat);
    hipLaunchKernelGGL(bn_finalize, dim3(1), dim3(128), 0, stream, stat, g[l],
                       bt[l], ss);
    hipLaunchKernelGGL((gemm_mfma<true, false, true>), dim3(GMB), dim3(256), 0,
                       stream, hbuf, wt[2 * l], b2[l], ss, ss + HID, xb,
                       nullptr);
  }

  // ---------------- Pool + final MLP ----------------
  hipMemsetAsync(pooled, 0, (size_t)NB * HID * sizeof(float), stream);
  hipLaunchKernelGGL(pool_kernel, dim3(POOL_NBLK), dim3(64), 0, stream, xb,
                     batch, pooled);
  hipLaunchKernelGGL(final_mlp, dim3(NB), dim3(128), 0, stream, pooled, Wf1,
                     bf1, Wf2, bf2, out);
}